// Round 7
// baseline (1254.200 us; speedup 1.0000x reference)
//
#include <hip/hip_runtime.h>
#include <hip/hip_bf16.h>
#include <math.h>

typedef __hip_bfloat16 bf16;

#define BB    32
#define HH    56
#define WWI   56
#define CC    192
#define NHH   6
#define WSS   7
#define NN    49
#define NWIN  64
#define HDD   32
#define LL    (HH*WWI)
#define ROWS  (BB*NWIN*NN)         // 100352
#define TOT   ((size_t)ROWS*CC)    // 19267584
#define SCALEQ 0.17677669529663687f

// canonical bf16 weight buffer element offsets
#define OFF_N1W   0
#define OFF_N1B   384
#define OFF_QKVW  768
#define OFF_QKVB  221952
#define OFF_RPB   223104
#define OFF_PROJW 225132
#define OFF_PROJB 298860
#define OFF_N2W   299244
#define OFF_N2B   299628
#define OFF_F1W   300012
#define OFF_F1B   594924
#define OFF_F2W   596460
#define OFF_F2B   891372

typedef __bf16 bf16x8v __attribute__((ext_vector_type(8)));
typedef float  f32x4   __attribute__((ext_vector_type(4)));

__device__ __forceinline__ float tof(bf16 v){ return __bfloat162float(v); }
__device__ __forceinline__ bf16  tob(float v){ return __float2bfloat16(v); }
__device__ __forceinline__ float xload(const float* p){ return *p; }
__device__ __forceinline__ float xload(const bf16*  p){ return tof(*p); }
__device__ __forceinline__ void  xstore(float* p, float v){ *p = v; }
__device__ __forceinline__ void  xstore(bf16*  p, float v){ *p = tob(v); }

__device__ __forceinline__ bf16x8v ldfrag(const bf16* p){
    return *(const bf16x8v*)p;
}
__device__ __forceinline__ unsigned short bfbits(float v){
    bf16 b = tob(v);
    return __builtin_bit_cast(unsigned short, b);
}
__device__ __forceinline__ bf16 mkbf(unsigned short u){
    return __builtin_bit_cast(bf16, u);
}

// A&S 7.1.26 erf, |eps| <= 1.5e-7; gelu exact form
__device__ __forceinline__ float fast_gelu(float x){
    float u = fabsf(x) * 0.70710678118f;
    float t = __builtin_amdgcn_rcpf(1.f + 0.3275911f*u);
    float p = t*(0.254829592f + t*(-0.284496736f + t*(1.421413741f +
              t*(-1.453152027f + t*1.061405429f))));
    float e = __expf(-u*u);
    float erfu = 1.f - p*e;
    float s = copysignf(erfu, x);
    return 0.5f*x*(1.f + s);
}

// ---------- dtype detect ----------
__global__ void k_detect(const unsigned short* __restrict__ w, int* __restrict__ flag){
    if (blockIdx.x == 0 && threadIdx.x == 0){
        int cnt = 0;
        for (int k = 0; k < 16; ++k){
            unsigned short u = w[2*k];
            if (u >= 0x3E00 && u <= 0x4100) ++cnt;
        }
        *flag = (cnt >= 8) ? 1 : 0;
    }
}

__global__ void k_canon(const void* __restrict__ src, bf16* __restrict__ dst,
                        int n, const int* __restrict__ flag){
    int i = blockIdx.x * blockDim.x + threadIdx.x;
    if (i >= n) return;
    if (*flag) dst[i] = ((const bf16*)src)[i];
    else       dst[i] = tob(((const float*)src)[i]);
}

template<typename XT>
__global__ void k_convert_in(const void* __restrict__ in, XT* __restrict__ X,
                             const int* __restrict__ flag){
    size_t i = (size_t)blockIdx.x * blockDim.x + threadIdx.x;
    if (i >= TOT) return;
    float v = (*flag) ? tof(((const bf16*)in)[i]) : ((const float*)in)[i];
    xstore(&X[i], v);
}

// ---------- LN1 + shift + window partition : wave-per-row, no LDS ----------
template<typename XT>
__global__ __launch_bounds__(256) void k_ln_part(const XT* __restrict__ X,
        const bf16* __restrict__ w, const bf16* __restrict__ bsh,
        bf16* __restrict__ Hwin, int shift){
    int wv = threadIdx.x >> 6, lane = threadIdx.x & 63;
    int row = blockIdx.x*4 + wv;                 // ROWS % 4 == 0
    int b   = row / (NWIN*NN);
    int win = (row / NN) % NWIN;
    int n   = row % NN;
    int wh = win >> 3, ww = win & 7;
    int iy = n / WSS, ix = n % WSS;
    int sy = (wh*WSS + iy + shift) % HH;
    int sx = (ww*WSS + ix + shift) % WWI;
    const XT* src = X + ((size_t)(b*LL + sy*WWI + sx))*CC;
    float v0 = xload(&src[lane]);
    float v1 = xload(&src[lane+64]);
    float v2 = xload(&src[lane+128]);
    float sm  = v0+v1+v2;
    float sm2 = v0*v0+v1*v1+v2*v2;
    #pragma unroll
    for (int st = 1; st < 64; st <<= 1){
        sm  += __shfl_xor(sm,  st);
        sm2 += __shfl_xor(sm2, st);
    }
    float mu  = sm * (1.f/CC);
    float inv = rsqrtf(sm2*(1.f/CC) - mu*mu + 1e-5f);
    bf16* dst = Hwin + (size_t)row*CC;
    dst[lane]     = tob((v0-mu)*inv*tof(w[lane])     + tof(bsh[lane]));
    dst[lane+64]  = tob((v1-mu)*inv*tof(w[lane+64])  + tof(bsh[lane+64]));
    dst[lane+128] = tob((v2-mu)*inv*tof(w[lane+128]) + tof(bsh[lane+128]));
}

// ---------- window attention, MFMA, 4-barrier structure ----------
__device__ __forceinline__ int mt0(int i){ return (i < 3) ? i*16 : 33; }

__global__ __launch_bounds__(512, 4) void k_attn(const bf16* __restrict__ Hwin,
        const bf16* __restrict__ qkvw, const bf16* __restrict__ qkvb,
        const bf16* __restrict__ rpb, bf16* __restrict__ AOut, int masked){
    __shared__ bf16 smem[31104];                 // 62208 B
    bf16* qls = smem;
    bf16* kls = smem + 9408;
    bf16* vT  = smem + 18816;
    bf16* Pls = smem;                            // alias q+k after barrier #2

    int t = threadIdx.x;
    int win  = blockIdx.x;
    int winl = win & (NWIN-1);
    int wh = winl >> 3, ww = winl & 7;
    int wv = t >> 6, lane = t & 63;
    int li16 = lane & 15, quad = lane >> 4;

    for (int idx = t; idx < 192*15; idx += 512){
        int d = idx / 15, tokp = 49 + idx % 15;
        vT[d*64 + (tokp ^ ((d&7)<<3))] = tob(0.f);
    }

    // ---- phase Q: QKV for ALL heads, one long phase ----
    {
        int p = wv & 1, c = wv >> 1;
        int m0a = mt0(2*p), m0b = mt0(2*p+1);
        const bf16* hg = Hwin + (size_t)win*NN*CC;
        bf16x8v afa[6], afb[6];
        #pragma unroll
        for (int kc = 0; kc < 6; ++kc){
            afa[kc] = ldfrag(hg + (m0a+li16)*CC + kc*32 + quad*8);
            afb[kc] = ldfrag(hg + (m0b+li16)*CC + kc*32 + quad*8);
        }
        #pragma unroll 3
        for (int j = 0; j < 9; ++j){
            int nt = c + 4*j;
            int col = nt*16 + li16;
            f32x4 acc0 = {0.f,0.f,0.f,0.f}, acc1 = {0.f,0.f,0.f,0.f};
            #pragma unroll
            for (int kc = 0; kc < 6; ++kc){
                bf16x8v bfr = ldfrag(qkvw + (size_t)col*CC + kc*32 + quad*8);
                acc0 = __builtin_amdgcn_mfma_f32_16x16x32_bf16(afa[kc], bfr, acc0, 0, 0, 0);
                acc1 = __builtin_amdgcn_mfma_f32_16x16x32_bf16(afb[kc], bfr, acc1, 0, 0, 0);
            }
            float bias = tof(qkvb[col]);
            int m  = col / CC;
            int cm = col - m*CC;
            #pragma unroll
            for (int r = 0; r < 4; ++r){
                int rowA = m0a + quad*4 + r;
                int rowB = m0b + quad*4 + r;
                float v0 = acc0[r] + bias, v1 = acc1[r] + bias;
                if (m == 0){
                    qls[rowA*CC + (cm ^ ((rowA&7)<<3))] = tob(v0*SCALEQ);
                    qls[rowB*CC + (cm ^ ((rowB&7)<<3))] = tob(v1*SCALEQ);
                } else if (m == 1){
                    kls[rowA*CC + (cm ^ ((rowA&7)<<3))] = tob(v0);
                    kls[rowB*CC + (cm ^ ((rowB&7)<<3))] = tob(v1);
                } else {
                    vT[cm*64 + (rowA ^ ((cm&7)<<3))] = tob(v0);
                    vT[cm*64 + (rowB ^ ((cm&7)<<3))] = tob(v1);
                }
            }
        }
    }
    __syncthreads();   // #1

    unsigned int pk[3][8];
    #pragma unroll
    for (int j = 0; j < 3; ++j){
        int id = wv + 8*j;
        int mt = id & 3, h = id >> 2;
        int m0 = mt0(mt);
        int rowq = m0 + li16;
        bf16x8v afr = ldfrag(qls + rowq*CC + ((h*32 + quad*8) ^ ((rowq&7)<<3)));
        f32x4 s[4];
        #pragma unroll
        for (int nt = 0; nt < 4; ++nt){
            int rowk = nt*16 + li16;
            bf16x8v bfr = ldfrag(kls + rowk*CC + ((h*32 + quad*8) ^ ((rowk&7)<<3)));
            f32x4 z = {0.f,0.f,0.f,0.f};
            s[nt] = __builtin_amdgcn_mfma_f32_16x16x32_bf16(afr, bfr, z, 0, 0, 0);
        }
        #pragma unroll
        for (int nt = 0; nt < 4; ++nt){
            int jj = nt*16 + li16;
            int valid = (jj < NN);
            int jc = valid ? jj : 48;
            int yj = (jc*37) >> 8, xj = jc - 7*yj;
            int lj = 0;
            if (masked){
                int ayj = wh*WSS + yj, axj = ww*WSS + xj;
                lj = ((ayj<49)?0:(ayj<53)?1:2)*3 + ((axj<49)?0:(axj<53)?1:2);
            }
            #pragma unroll
            for (int r = 0; r < 4; ++r){
                int i = m0 + quad*4 + r;
                int yi = (i*37) >> 8, xi = i - 7*yi;
                int ridx = (yi - yj + 6)*13 + (xi - xj + 6);
                float v = s[nt][r] + tof(rpb[ridx*NHH + h]);
                if (masked){
                    int ayi = wh*WSS + yi, axi = ww*WSS + xi;
                    int li = ((ayi<49)?0:(ayi<53)?1:2)*3 + ((axi<49)?0:(axi<53)?1:2);
                    if (li != lj) v -= 100.f;
                }
                s[nt][r] = valid ? v : -1e30f;
            }
        }
        float mx[4], sm[4];
        #pragma unroll
        for (int r = 0; r < 4; ++r)
            mx[r] = fmaxf(fmaxf(s[0][r], s[1][r]), fmaxf(s[2][r], s[3][r]));
        #pragma unroll
        for (int st = 1; st < 16; st <<= 1){
            #pragma unroll
            for (int r = 0; r < 4; ++r) mx[r] = fmaxf(mx[r], __shfl_xor(mx[r], st));
        }
        #pragma unroll
        for (int nt = 0; nt < 4; ++nt){
            #pragma unroll
            for (int r = 0; r < 4; ++r) s[nt][r] = __expf(s[nt][r] - mx[r]);
        }
        #pragma unroll
        for (int r = 0; r < 4; ++r) sm[r] = (s[0][r]+s[1][r]) + (s[2][r]+s[3][r]);
        #pragma unroll
        for (int st = 1; st < 16; st <<= 1){
            #pragma unroll
            for (int r = 0; r < 4; ++r) sm[r] += __shfl_xor(sm[r], st);
        }
        #pragma unroll
        for (int r = 0; r < 4; ++r) sm[r] = 1.f / sm[r];
        #pragma unroll
        for (int nt = 0; nt < 4; ++nt){
            #pragma unroll
            for (int rr = 0; rr < 2; ++rr){
                unsigned int u0 = bfbits(s[nt][2*rr]   * sm[2*rr]);
                unsigned int u1 = bfbits(s[nt][2*rr+1] * sm[2*rr+1]);
                pk[j][nt*2+rr] = (u1 << 16) | u0;
            }
        }
    }
    __syncthreads();  // #2

    #pragma unroll
    for (int j = 0; j < 3; ++j){
        int id = wv + 8*j;
        int m0 = mt0(id & 3), h = id >> 2;
        #pragma unroll
        for (int nt = 0; nt < 4; ++nt){
            int jj = nt*16 + li16;
            #pragma unroll
            for (int rr = 0; rr < 2; ++rr){
                unsigned int u = pk[j][nt*2+rr];
                int tok0 = m0 + quad*4 + 2*rr;
                int tok1 = tok0 + 1;
                Pls[(h*NN + tok0)*64 + (jj ^ ((tok0&7)<<3))] = mkbf((unsigned short)(u & 0xffff));
                Pls[(h*NN + tok1)*64 + (jj ^ ((tok1&7)<<3))] = mkbf((unsigned short)(u >> 16));
            }
        }
    }
    __syncthreads();  // #3

    {
        int mt = wv & 3, nto = wv >> 2;
        int m0 = mt0(mt), n0 = nto*16;
        #pragma unroll
        for (int h = 0; h < NHH; ++h){
            f32x4 acc = {0.f,0.f,0.f,0.f};
            #pragma unroll
            for (int kc = 0; kc < 2; ++kc){
                int rowp = m0 + li16;
                bf16x8v afr = ldfrag(Pls + (h*NN + rowp)*64 + ((kc*32 + quad*8) ^ ((rowp&7)<<3)));
                int rowv = h*HDD + n0 + li16;
                bf16x8v bfr = ldfrag(vT + rowv*64 + ((kc*32 + quad*8) ^ ((rowv&7)<<3)));
                acc = __builtin_amdgcn_mfma_f32_16x16x32_bf16(afr, bfr, acc, 0, 0, 0);
            }
            #pragma unroll
            for (int r = 0; r < 4; ++r){
                int tok = m0 + quad*4 + r;
                AOut[(size_t)win*NN*CC + tok*CC + h*HDD + n0 + li16] = tob(acc[r]);
            }
        }
    }
}

// ---------- proj (MFMA) + window reverse + roll-by-WS bug + residual ----------
// 32-row blocks (round-4 proven config)
#define AS_STRIDE 200
template<typename XT>
__global__ __launch_bounds__(256) void k_proj_res(const bf16* __restrict__ AOut,
        const bf16* __restrict__ pw, const bf16* __restrict__ pb,
        XT* __restrict__ X, int shift){
    __shared__ bf16 as[32*AS_STRIDE];
    int t = threadIdx.x;
    int row0 = blockIdx.x * 32;
    for (int idx = t; idx < 32*24; idx += 256){
        int r = idx / 24, c8 = idx % 24;
        *(bf16x8v*)(as + r*AS_STRIDE + c8*8) = ldfrag(AOut + (size_t)(row0 + r)*CC + c8*8);
    }
    __syncthreads();
    int wv = t >> 6, lane = t & 63;
    int li16 = lane & 15, quad = lane >> 4;
    int roll = (shift > 0) ? WSS : 0;
    for (int nt = 0; nt < 3; ++nt){
        int n0 = wv*48 + nt*16;
        int col = n0 + li16;
        bf16x8v bfr[6];
        #pragma unroll
        for (int kc = 0; kc < 6; ++kc)
            bfr[kc] = ldfrag(pw + (size_t)col*CC + kc*32 + quad*8);
        float bias = tof(pb[col]);
        for (int mt = 0; mt < 2; ++mt){
            int m0 = mt*16;
            f32x4 acc = {0.f,0.f,0.f,0.f};
            #pragma unroll
            for (int kc = 0; kc < 6; ++kc){
                bf16x8v afr = ldfrag(as + (m0 + li16)*AS_STRIDE + kc*32 + quad*8);
                acc = __builtin_amdgcn_mfma_f32_16x16x32_bf16(afr, bfr[kc], acc, 0, 0, 0);
            }
            #pragma unroll
            for (int r = 0; r < 4; ++r){
                int grow = row0 + m0 + quad*4 + r;
                int b   = grow / (NWIN*NN);
                int rem = grow % (NWIN*NN);
                int win = rem / NN;
                int n   = rem % NN;
                int wh = win >> 3, ww = win & 7;
                int iy = n / WSS, ix = n % WSS;
                int y = (wh*WSS + iy + roll) % HH;
                int x = (ww*WSS + ix + roll) % WWI;
                size_t idx = ((size_t)(b*LL + y*WWI + x))*CC + col;
                xstore(&X[idx], xload(&X[idx]) + acc[r] + bias);
            }
        }
    }
}

// ---------- LN2 + FC1(MFMA) + GELU + FC2(MFMA) + residual ----------
// 512 threads / 8 waves: wave = (row-half rh) x (col-group wc).
// Per-lane acc2[3][2]=24 f32 (half of the 256-thr version) -> fits the
// 128-reg cap of launch_bounds(512,4) with NO spill (r5 lesson: 256-thr
// 48-f32 acc + cap 128 spills; (256,3) caps occupancy at 26%).
// 4 passes x 192 cols (r4-proven). LDS 2x24576B = 49152 -> 2 blocks/CU,
// 16 waves/CU (50% occ).
template<typename XT>
__global__ __launch_bounds__(512, 4) void k_mlp(XT* __restrict__ X,
        const bf16* __restrict__ n2w, const bf16* __restrict__ n2b,
        const bf16* __restrict__ w1, const bf16* __restrict__ b1,
        const bf16* __restrict__ w2, const bf16* __restrict__ b2,
        void* __restrict__ outp, const int* __restrict__ flag){
    __shared__ bf16 xin[64*192];
    __shared__ bf16 h1p[64*192];
    int t = threadIdx.x;
    int wv = t >> 6, lane = t & 63;
    int li16 = lane & 15, quad = lane >> 4;
    int rh = wv >> 2;                 // row half: rows rh*32 .. rh*32+31
    int wc = wv & 3;                  // col group: cols wc*48 .. wc*48+47
    size_t row0 = (size_t)blockIdx.x * 64;

    // ---- LN2: wave-per-row, 8 rows per wave, no barriers ----
    {
        float nw0 = tof(n2w[lane]), nw1 = tof(n2w[lane+64]), nw2 = tof(n2w[lane+128]);
        float nb0 = tof(n2b[lane]), nb1 = tof(n2b[lane+64]), nb2 = tof(n2b[lane+128]);
        #pragma unroll 4
        for (int i = 0; i < 8; ++i){
            int r = wv*8 + i;
            const XT* xr = X + (row0 + r)*CC;
            float v0 = xload(&xr[lane]);
            float v1 = xload(&xr[lane+64]);
            float v2 = xload(&xr[lane+128]);
            float sm  = v0+v1+v2;
            float sm2 = v0*v0+v1*v1+v2*v2;
            #pragma unroll
            for (int st = 1; st < 64; st <<= 1){
                sm  += __shfl_xor(sm,  st);
                sm2 += __shfl_xor(sm2, st);
            }
            float mu  = sm * (1.f/CC);
            float inv = rsqrtf(sm2*(1.f/CC) - mu*mu + 1e-5f);
            int swz = (r&7)<<3;
            bf16* xrow = xin + r*192;
            xrow[lane        ^ swz] = tob((v0-mu)*inv*nw0 + nb0);
            xrow[(lane+64)   ^ swz] = tob((v1-mu)*inv*nw1 + nb1);
            xrow[(lane+128)  ^ swz] = tob((v2-mu)*inv*nw2 + nb2);
        }
    }
    __syncthreads();

    int sw = (li16 & 7) << 3;
    f32x4 acc2[3][2];                       // [j][rowset], persistent
    #pragma unroll
    for (int j = 0; j < 3; ++j)
        #pragma unroll
        for (int m = 0; m < 2; ++m)
            acc2[j][m] = (f32x4){0.f,0.f,0.f,0.f};

    #pragma unroll 1
    for (int pass = 0; pass < 4; ++pass){
        // ---- FC1: 192 cols this pass; wave owns 3 j x 2 rowsets ----
        #pragma unroll
        for (int j = 0; j < 3; ++j){
            int cl  = wc*48 + j*16 + li16;         // 0..191
            int col = pass*192 + cl;
            f32x4 a1[2];
            a1[0] = (f32x4){0.f,0.f,0.f,0.f};
            a1[1] = (f32x4){0.f,0.f,0.f,0.f};
            #pragma unroll
            for (int kc = 0; kc < 6; ++kc){
                bf16x8v bfr = ldfrag(w1 + (size_t)col*CC + kc*32 + quad*8);
                #pragma unroll
                for (int m = 0; m < 2; ++m){
                    bf16x8v af = ldfrag(xin + (rh*32 + m*16 + li16)*192 + ((kc*32 + quad*8) ^ sw));
                    a1[m] = __builtin_amdgcn_mfma_f32_16x16x32_bf16(af, bfr, a1[m], 0, 0, 0);
                }
            }
            float bb = tof(b1[col]);
            #pragma unroll
            for (int m = 0; m < 2; ++m){
                #pragma unroll
                for (int r = 0; r < 4; ++r){
                    int row = rh*32 + m*16 + quad*4 + r;
                    h1p[row*192 + (cl ^ ((row&7)<<3))] = tob(fast_gelu(a1[m][r] + bb));
                }
            }
        }
        __syncthreads();        // h1 pass-tile ready
        // ---- FC2 partial accumulate: K-slice = 192 (6 kc), af hoisted ----
        #pragma unroll
        for (int kc = 0; kc < 6; ++kc){
            bf16x8v af[2];
            #pragma unroll
            for (int m = 0; m < 2; ++m)
                af[m] = ldfrag(h1p + (rh*32 + m*16 + li16)*192 + ((kc*32 + quad*8) ^ sw));
            int kg = pass*6 + kc;
            #pragma unroll
            for (int j = 0; j < 3; ++j){
                int col = wc*48 + j*16 + li16;
                bf16x8v bfr = ldfrag(w2 + (size_t)col*768 + kg*32 + quad*8);
                #pragma unroll
                for (int m = 0; m < 2; ++m)
                    acc2[j][m] = __builtin_amdgcn_mfma_f32_16x16x32_bf16(af[m], bfr, acc2[j][m], 0, 0, 0);
            }
        }
        __syncthreads();        // FC2 reads done before next pass overwrites h1p
    }

    // ---- writeout: residual; final layer writes converted output ----
    int wout = (outp != nullptr);
    int fl = wout ? *flag : 0;
    #pragma unroll
    for (int j = 0; j < 3; ++j){
        int col = wc*48 + j*16 + li16;
        float bias = tof(b2[col]);
        #pragma unroll
        for (int m = 0; m < 2; ++m){
            #pragma unroll
            for (int r = 0; r < 4; ++r){
                size_t idx = (row0 + rh*32 + m*16 + quad*4 + r)*CC + col;
                float v = xload(&X[idx]) + acc2[j][m][r] + bias;
                if (wout){
                    if (fl) ((bf16*)outp)[idx] = tob(v);
                    else    ((float*)outp)[idx] = v;
                } else {
                    xstore(&X[idx], v);
                }
            }
        }
    }
}

// ---------- driver ----------
template<typename XT>
static void run_pipeline(const bf16* wb, const void* xin, int* flag,
                         XT* X, bf16* Hwin, bf16* AOut, void* out,
                         hipStream_t stream){
    k_convert_in<XT><<<(int)(TOT/256), 256, 0, stream>>>(xin, X, flag);
    for (int i = 0; i < 2; ++i){
        int shift = i ? (WSS/2) : 0;
        k_ln_part<XT><<<ROWS/4, 256, 0, stream>>>(X, wb+OFF_N1W + i*CC,
                wb+OFF_N1B + i*CC, Hwin, shift);
        k_attn<<<BB*NWIN, 512, 0, stream>>>(Hwin,
                wb+OFF_QKVW + (size_t)i*3*CC*CC, wb+OFF_QKVB + (size_t)i*3*CC,
                wb+OFF_RPB + (size_t)i*169*NHH, AOut, i);
        k_proj_res<XT><<<ROWS/32, 256, 0, stream>>>(AOut,
                wb+OFF_PROJW + (size_t)i*CC*CC, wb+OFF_PROJB + i*CC, X, shift);
        k_mlp<XT><<<ROWS/64, 512, 0, stream>>>(X,
                wb+OFF_N2W + i*CC, wb+OFF_N2B + i*CC,
                wb+OFF_F1W + (size_t)i*4*CC*CC, wb+OFF_F1B + (size_t)i*4*CC,
                wb+OFF_F2W + (size_t)i*CC*4*CC, wb+OFF_F2B + i*CC,
                (i == 1) ? out : nullptr, flag);
    }
}

extern "C" void kernel_launch(void* const* d_in, const int* in_sizes, int n_in,
                              void* d_out, int out_size, void* d_ws, size_t ws_size,
                              hipStream_t stream){
    char* p = (char*)d_ws;
    int*  flag = (int*)p;
    bf16* wb   = (bf16*)(p + 16);
    char* q    = p + 16 + (2u<<20);

    k_detect<<<1, 64, 0, stream>>>((const unsigned short*)d_in[1], flag);

    static const int widx[13] = {1,2,3,4,5,6,7,8,9,10,11,12,13};
    static const int woff[13] = {OFF_N1W,OFF_N1B,OFF_QKVW,OFF_QKVB,OFF_RPB,
                                 OFF_PROJW,OFF_PROJB,OFF_N2W,OFF_N2B,
                                 OFF_F1W,OFF_F1B,OFF_F2W,OFF_F2B};
    static const int wsz[13]  = {384,384,221184,1152,2028,73728,384,384,384,
                                 294912,1536,294912,384};
    for (int k = 0; k < 13; ++k)
        k_canon<<<(wsz[k]+255)/256, 256, 0, stream>>>(d_in[widx[k]], wb+woff[k],
                                                      wsz[k], flag);

    size_t needF32 = 16 + (2u<<20) + TOT*4 + TOT*2 + TOT*2;
    if (ws_size >= needF32){
        float* X   = (float*)q;       q += TOT*4;
        bf16* Hwin = (bf16*)q;        q += TOT*2;
        bf16* AOut = (bf16*)q;
        run_pipeline<float>(wb, d_in[0], flag, X, Hwin, AOut, d_out, stream);
    } else {
        bf16* X    = (bf16*)q;        q += TOT*2;
        bf16* Hwin = (bf16*)q;        q += TOT*2;
        bf16* AOut = (bf16*)q;
        run_pipeline<bf16>(wb, d_in[0], flag, X, Hwin, AOut, d_out, stream);
    }
}

// Round 9
// 1132.781 us; speedup vs baseline: 1.1072x; 1.1072x over previous
//
#include <hip/hip_runtime.h>
#include <hip/hip_bf16.h>
#include <math.h>

typedef __hip_bfloat16 bf16;

#define BB    32
#define HH    56
#define WWI   56
#define CC    192
#define NHH   6
#define WSS   7
#define NN    49
#define NWIN  64
#define HDD   32
#define LL    (HH*WWI)
#define ROWS  (BB*NWIN*NN)         // 100352
#define TOT   ((size_t)ROWS*CC)    // 19267584
#define SCALEQ 0.17677669529663687f

// canonical bf16 weight buffer element offsets
#define OFF_N1W   0
#define OFF_N1B   384
#define OFF_QKVW  768
#define OFF_QKVB  221952
#define OFF_RPB   223104
#define OFF_PROJW 225132
#define OFF_PROJB 298860
#define OFF_N2W   299244
#define OFF_N2B   299628
#define OFF_F1W   300012
#define OFF_F1B   594924
#define OFF_F2W   596460
#define OFF_F2B   891372

typedef __bf16 bf16x8v __attribute__((ext_vector_type(8)));
typedef float  f32x4   __attribute__((ext_vector_type(4)));

__device__ __forceinline__ float tof(bf16 v){ return __bfloat162float(v); }
__device__ __forceinline__ bf16  tob(float v){ return __float2bfloat16(v); }
__device__ __forceinline__ float xload(const float* p){ return *p; }
__device__ __forceinline__ float xload(const bf16*  p){ return tof(*p); }
__device__ __forceinline__ void  xstore(float* p, float v){ *p = v; }
__device__ __forceinline__ void  xstore(bf16*  p, float v){ *p = tob(v); }

__device__ __forceinline__ bf16x8v ldfrag(const bf16* p){
    return *(const bf16x8v*)p;
}
__device__ __forceinline__ unsigned short bfbits(float v){
    bf16 b = tob(v);
    return __builtin_bit_cast(unsigned short, b);
}
__device__ __forceinline__ bf16 mkbf(unsigned short u){
    return __builtin_bit_cast(bf16, u);
}

// dynamic-dtype load: dynf<0 -> typed XT; dynf==0 -> float; dynf==1 -> bf16
template<typename XT>
__device__ __forceinline__ float ldx(const void* p, size_t i, int dynf){
    if (dynf < 0) return xload(((const XT*)p) + i);
    return dynf ? tof(((const bf16*)p)[i]) : ((const float*)p)[i];
}

// A&S 7.1.26 erf, |eps| <= 1.5e-7; gelu exact form
__device__ __forceinline__ float fast_gelu(float x){
    float u = fabsf(x) * 0.70710678118f;
    float t = __builtin_amdgcn_rcpf(1.f + 0.3275911f*u);
    float p = t*(0.254829592f + t*(-0.284496736f + t*(1.421413741f +
              t*(-1.453152027f + t*1.061405429f))));
    float e = __expf(-u*u);
    float erfu = 1.f - p*e;
    float s = copysignf(erfu, x);
    return 0.5f*x*(1.f + s);
}

// ---------- dtype detect ----------
__global__ void k_detect(const unsigned short* __restrict__ w, int* __restrict__ flag){
    if (blockIdx.x == 0 && threadIdx.x == 0){
        int cnt = 0;
        for (int k = 0; k < 16; ++k){
            unsigned short u = w[2*k];
            if (u >= 0x3E00 && u <= 0x4100) ++cnt;
        }
        *flag = (cnt >= 8) ? 1 : 0;
    }
}

__global__ void k_canon(const void* __restrict__ src, bf16* __restrict__ dst,
                        int n, const int* __restrict__ flag){
    int i = blockIdx.x * blockDim.x + threadIdx.x;
    if (i >= n) return;
    if (*flag) dst[i] = ((const bf16*)src)[i];
    else       dst[i] = tob(((const float*)src)[i]);
}

// ---------- LN1 + shift + window partition : wave-per-row, no LDS ----------
// src: layer0 = raw input (dtype via flag), layer1 = X (typed XT). Read-only.
template<typename XT>
__global__ __launch_bounds__(256) void k_ln_part(const void* __restrict__ src,
        int dynsrc, const int* __restrict__ flag,
        const bf16* __restrict__ w, const bf16* __restrict__ bsh,
        bf16* __restrict__ Hwin, int shift){
    int dynf = dynsrc ? flag[0] : -1;
    int wv = threadIdx.x >> 6, lane = threadIdx.x & 63;
    int row = blockIdx.x*4 + wv;                 // ROWS % 4 == 0
    int b   = row / (NWIN*NN);
    int win = (row / NN) % NWIN;
    int n   = row % NN;
    int wh = win >> 3, ww = win & 7;
    int iy = n / WSS, ix = n % WSS;
    int sy = (wh*WSS + iy + shift) % HH;
    int sx = (ww*WSS + ix + shift) % WWI;
    size_t base = ((size_t)(b*LL + sy*WWI + sx))*CC;
    float v0 = ldx<XT>(src, base + lane,       dynf);
    float v1 = ldx<XT>(src, base + lane + 64,  dynf);
    float v2 = ldx<XT>(src, base + lane + 128, dynf);
    float sm  = v0+v1+v2;
    float sm2 = v0*v0+v1*v1+v2*v2;
    #pragma unroll
    for (int st = 1; st < 64; st <<= 1){
        sm  += __shfl_xor(sm,  st);
        sm2 += __shfl_xor(sm2, st);
    }
    float mu  = sm * (1.f/CC);
    float inv = rsqrtf(sm2*(1.f/CC) - mu*mu + 1e-5f);
    bf16* dst = Hwin + (size_t)row*CC;
    dst[lane]     = tob((v0-mu)*inv*tof(w[lane])     + tof(bsh[lane]));
    dst[lane+64]  = tob((v1-mu)*inv*tof(w[lane+64])  + tof(bsh[lane+64]));
    dst[lane+128] = tob((v2-mu)*inv*tof(w[lane+128]) + tof(bsh[lane+128]));
}

// ---------- window attention, MFMA, 4-barrier structure ----------
__device__ __forceinline__ int mt0(int i){ return (i < 3) ? i*16 : 33; }

__global__ __launch_bounds__(512, 4) void k_attn(const bf16* __restrict__ Hwin,
        const bf16* __restrict__ qkvw, const bf16* __restrict__ qkvb,
        const bf16* __restrict__ rpb, bf16* __restrict__ AOut, int masked){
    __shared__ bf16 smem[31104];                 // 62208 B
    bf16* qls = smem;
    bf16* kls = smem + 9408;
    bf16* vT  = smem + 18816;
    bf16* Pls = smem;                            // alias q+k after barrier #2

    int t = threadIdx.x;
    int win  = blockIdx.x;
    int winl = win & (NWIN-1);
    int wh = winl >> 3, ww = winl & 7;
    int wv = t >> 6, lane = t & 63;
    int li16 = lane & 15, quad = lane >> 4;

    for (int idx = t; idx < 192*15; idx += 512){
        int d = idx / 15, tokp = 49 + idx % 15;
        vT[d*64 + (tokp ^ ((d&7)<<3))] = tob(0.f);
    }

    // ---- phase Q: QKV for ALL heads, one long phase ----
    {
        int p = wv & 1, c = wv >> 1;
        int m0a = mt0(2*p), m0b = mt0(2*p+1);
        const bf16* hg = Hwin + (size_t)win*NN*CC;
        bf16x8v afa[6], afb[6];
        #pragma unroll
        for (int kc = 0; kc < 6; ++kc){
            afa[kc] = ldfrag(hg + (m0a+li16)*CC + kc*32 + quad*8);
            afb[kc] = ldfrag(hg + (m0b+li16)*CC + kc*32 + quad*8);
        }
        #pragma unroll 3
        for (int j = 0; j < 9; ++j){
            int nt = c + 4*j;
            int col = nt*16 + li16;
            f32x4 acc0 = {0.f,0.f,0.f,0.f}, acc1 = {0.f,0.f,0.f,0.f};
            #pragma unroll
            for (int kc = 0; kc < 6; ++kc){
                bf16x8v bfr = ldfrag(qkvw + (size_t)col*CC + kc*32 + quad*8);
                acc0 = __builtin_amdgcn_mfma_f32_16x16x32_bf16(afa[kc], bfr, acc0, 0, 0, 0);
                acc1 = __builtin_amdgcn_mfma_f32_16x16x32_bf16(afb[kc], bfr, acc1, 0, 0, 0);
            }
            float bias = tof(qkvb[col]);
            int m  = col / CC;
            int cm = col - m*CC;
            #pragma unroll
            for (int r = 0; r < 4; ++r){
                int rowA = m0a + quad*4 + r;
                int rowB = m0b + quad*4 + r;
                float v0 = acc0[r] + bias, v1 = acc1[r] + bias;
                if (m == 0){
                    qls[rowA*CC + (cm ^ ((rowA&7)<<3))] = tob(v0*SCALEQ);
                    qls[rowB*CC + (cm ^ ((rowB&7)<<3))] = tob(v1*SCALEQ);
                } else if (m == 1){
                    kls[rowA*CC + (cm ^ ((rowA&7)<<3))] = tob(v0);
                    kls[rowB*CC + (cm ^ ((rowB&7)<<3))] = tob(v1);
                } else {
                    vT[cm*64 + (rowA ^ ((cm&7)<<3))] = tob(v0);
                    vT[cm*64 + (rowB ^ ((cm&7)<<3))] = tob(v1);
                }
            }
        }
    }
    __syncthreads();   // #1

    unsigned int pk[3][8];
    #pragma unroll
    for (int j = 0; j < 3; ++j){
        int id = wv + 8*j;
        int mt = id & 3, h = id >> 2;
        int m0 = mt0(mt);
        int rowq = m0 + li16;
        bf16x8v afr = ldfrag(qls + rowq*CC + ((h*32 + quad*8) ^ ((rowq&7)<<3)));
        f32x4 s[4];
        #pragma unroll
        for (int nt = 0; nt < 4; ++nt){
            int rowk = nt*16 + li16;
            bf16x8v bfr = ldfrag(kls + rowk*CC + ((h*32 + quad*8) ^ ((rowk&7)<<3)));
            f32x4 z = {0.f,0.f,0.f,0.f};
            s[nt] = __builtin_amdgcn_mfma_f32_16x16x32_bf16(afr, bfr, z, 0, 0, 0);
        }
        #pragma unroll
        for (int nt = 0; nt < 4; ++nt){
            int jj = nt*16 + li16;
            int valid = (jj < NN);
            int jc = valid ? jj : 48;
            int yj = (jc*37) >> 8, xj = jc - 7*yj;
            int lj = 0;
            if (masked){
                int ayj = wh*WSS + yj, axj = ww*WSS + xj;
                lj = ((ayj<49)?0:(ayj<53)?1:2)*3 + ((axj<49)?0:(axj<53)?1:2);
            }
            #pragma unroll
            for (int r = 0; r < 4; ++r){
                int i = m0 + quad*4 + r;
                int yi = (i*37) >> 8, xi = i - 7*yi;
                int ridx = (yi - yj + 6)*13 + (xi - xj + 6);
                float v = s[nt][r] + tof(rpb[ridx*NHH + h]);
                if (masked){
                    int ayi = wh*WSS + yi, axi = ww*WSS + xi;
                    int li = ((ayi<49)?0:(ayi<53)?1:2)*3 + ((axi<49)?0:(axi<53)?1:2);
                    if (li != lj) v -= 100.f;
                }
                s[nt][r] = valid ? v : -1e30f;
            }
        }
        float mx[4], sm[4];
        #pragma unroll
        for (int r = 0; r < 4; ++r)
            mx[r] = fmaxf(fmaxf(s[0][r], s[1][r]), fmaxf(s[2][r], s[3][r]));
        #pragma unroll
        for (int st = 1; st < 16; st <<= 1){
            #pragma unroll
            for (int r = 0; r < 4; ++r) mx[r] = fmaxf(mx[r], __shfl_xor(mx[r], st));
        }
        #pragma unroll
        for (int nt = 0; nt < 4; ++nt){
            #pragma unroll
            for (int r = 0; r < 4; ++r) s[nt][r] = __expf(s[nt][r] - mx[r]);
        }
        #pragma unroll
        for (int r = 0; r < 4; ++r) sm[r] = (s[0][r]+s[1][r]) + (s[2][r]+s[3][r]);
        #pragma unroll
        for (int st = 1; st < 16; st <<= 1){
            #pragma unroll
            for (int r = 0; r < 4; ++r) sm[r] += __shfl_xor(sm[r], st);
        }
        #pragma unroll
        for (int r = 0; r < 4; ++r) sm[r] = 1.f / sm[r];
        #pragma unroll
        for (int nt = 0; nt < 4; ++nt){
            #pragma unroll
            for (int rr = 0; rr < 2; ++rr){
                unsigned int u0 = bfbits(s[nt][2*rr]   * sm[2*rr]);
                unsigned int u1 = bfbits(s[nt][2*rr+1] * sm[2*rr+1]);
                pk[j][nt*2+rr] = (u1 << 16) | u0;
            }
        }
    }
    __syncthreads();  // #2

    #pragma unroll
    for (int j = 0; j < 3; ++j){
        int id = wv + 8*j;
        int m0 = mt0(id & 3), h = id >> 2;
        #pragma unroll
        for (int nt = 0; nt < 4; ++nt){
            int jj = nt*16 + li16;
            #pragma unroll
            for (int rr = 0; rr < 2; ++rr){
                unsigned int u = pk[j][nt*2+rr];
                int tok0 = m0 + quad*4 + 2*rr;
                int tok1 = tok0 + 1;
                Pls[(h*NN + tok0)*64 + (jj ^ ((tok0&7)<<3))] = mkbf((unsigned short)(u & 0xffff));
                Pls[(h*NN + tok1)*64 + (jj ^ ((tok1&7)<<3))] = mkbf((unsigned short)(u >> 16));
            }
        }
    }
    __syncthreads();  // #3

    {
        int mt = wv & 3, nto = wv >> 2;
        int m0 = mt0(mt), n0 = nto*16;
        #pragma unroll
        for (int h = 0; h < NHH; ++h){
            f32x4 acc = {0.f,0.f,0.f,0.f};
            #pragma unroll
            for (int kc = 0; kc < 2; ++kc){
                int rowp = m0 + li16;
                bf16x8v afr = ldfrag(Pls + (h*NN + rowp)*64 + ((kc*32 + quad*8) ^ ((rowp&7)<<3)));
                int rowv = h*HDD + n0 + li16;
                bf16x8v bfr = ldfrag(vT + rowv*64 + ((kc*32 + quad*8) ^ ((rowv&7)<<3)));
                acc = __builtin_amdgcn_mfma_f32_16x16x32_bf16(afr, bfr, acc, 0, 0, 0);
            }
            #pragma unroll
            for (int r = 0; r < 4; ++r){
                int tok = m0 + quad*4 + r;
                AOut[(size_t)win*NN*CC + tok*CC + h*HDD + n0 + li16] = tob(acc[r]);
            }
        }
    }
}

// ---------- proj (MFMA) + window reverse + roll-by-WS bug + residual ----------
// 32-row blocks. Residual: layer0 reads raw input via rsrc (DISTINCT buffer);
// layer1 reads through the X pointer itself (rsrc aliases X and is then never
// dereferenced -> no restrict UB; round-8's dual-pointer read was UB and broke).
#define AS_STRIDE 200
template<typename XT>
__global__ __launch_bounds__(256) void k_proj_res(const bf16* __restrict__ AOut,
        const bf16* __restrict__ pw, const bf16* __restrict__ pb,
        const void* rsrc, int dynsrc, const int* __restrict__ flag,
        XT* __restrict__ X, int shift){
    __shared__ bf16 as[32*AS_STRIDE];
    int fl = dynsrc ? flag[0] : 0;
    int t = threadIdx.x;
    int row0 = blockIdx.x * 32;
    for (int idx = t; idx < 32*24; idx += 256){
        int r = idx / 24, c8 = idx % 24;
        *(bf16x8v*)(as + r*AS_STRIDE + c8*8) = ldfrag(AOut + (size_t)(row0 + r)*CC + c8*8);
    }
    __syncthreads();
    int wv = t >> 6, lane = t & 63;
    int li16 = lane & 15, quad = lane >> 4;
    int roll = (shift > 0) ? WSS : 0;
    for (int nt = 0; nt < 3; ++nt){
        int n0 = wv*48 + nt*16;
        int col = n0 + li16;
        bf16x8v bfr[6];
        #pragma unroll
        for (int kc = 0; kc < 6; ++kc)
            bfr[kc] = ldfrag(pw + (size_t)col*CC + kc*32 + quad*8);
        float bias = tof(pb[col]);
        for (int mt = 0; mt < 2; ++mt){
            int m0 = mt*16;
            f32x4 acc = {0.f,0.f,0.f,0.f};
            #pragma unroll
            for (int kc = 0; kc < 6; ++kc){
                bf16x8v afr = ldfrag(as + (m0 + li16)*AS_STRIDE + kc*32 + quad*8);
                acc = __builtin_amdgcn_mfma_f32_16x16x32_bf16(afr, bfr[kc], acc, 0, 0, 0);
            }
            #pragma unroll
            for (int r = 0; r < 4; ++r){
                int grow = row0 + m0 + quad*4 + r;
                int b   = grow / (NWIN*NN);
                int rem = grow % (NWIN*NN);
                int win = rem / NN;
                int n   = rem % NN;
                int wh = win >> 3, ww = win & 7;
                int iy = n / WSS, ix = n % WSS;
                int y = (wh*WSS + iy + roll) % HH;
                int x = (ww*WSS + ix + roll) % WWI;
                size_t idx = ((size_t)(b*LL + y*WWI + x))*CC + col;
                float res;
                if (dynsrc)
                    res = fl ? tof(((const bf16*)rsrc)[idx])
                             : ((const float*)rsrc)[idx];
                else
                    res = xload(&X[idx]);
                xstore(&X[idx], res + acc[r] + bias);
            }
        }
    }
}

// ---------- LN2 + FC1(MFMA) + GELU + FC2(MFMA) + residual ----------
// ROUND-4 PROVEN CONFIG (225us): M=64, 4 passes x 192 cols, 256 thr, (256,3).
// FC1 j-sequential (a1[4]=16 regs live next to acc2[3][4]=48 -> no spill).
// LDS: xin 64x192 (24576B) + h1p 64x192 (24576B) = 49152B.
// If outp != null (final layer): write converted output, skip dead X store.
template<typename XT>
__global__ __launch_bounds__(256, 3) void k_mlp(XT* __restrict__ X,
        const bf16* __restrict__ n2w, const bf16* __restrict__ n2b,
        const bf16* __restrict__ w1, const bf16* __restrict__ b1,
        const bf16* __restrict__ w2, const bf16* __restrict__ b2,
        void* __restrict__ outp, const int* __restrict__ flag){
    __shared__ bf16 xin[64*192];
    __shared__ bf16 h1p[64*192];
    int t = threadIdx.x;
    int wv = t >> 6, lane = t & 63;
    int li16 = lane & 15, quad = lane >> 4;
    size_t row0 = (size_t)blockIdx.x * 64;

    // ---- LN2: wave-per-row, 16 rows per wave, no barriers ----
    {
        float nw0 = tof(n2w[lane]), nw1 = tof(n2w[lane+64]), nw2 = tof(n2w[lane+128]);
        float nb0 = tof(n2b[lane]), nb1 = tof(n2b[lane+64]), nb2 = tof(n2b[lane+128]);
        #pragma unroll 4
        for (int i = 0; i < 16; ++i){
            int r = wv*16 + i;
            const XT* xr = X + (row0 + r)*CC;
            float v0 = xload(&xr[lane]);
            float v1 = xload(&xr[lane+64]);
            float v2 = xload(&xr[lane+128]);
            float sm  = v0+v1+v2;
            float sm2 = v0*v0+v1*v1+v2*v2;
            #pragma unroll
            for (int st = 1; st < 64; st <<= 1){
                sm  += __shfl_xor(sm,  st);
                sm2 += __shfl_xor(sm2, st);
            }
            float mu  = sm * (1.f/CC);
            float inv = rsqrtf(sm2*(1.f/CC) - mu*mu + 1e-5f);
            int swz = (r&7)<<3;
            bf16* xrow = xin + r*192;
            xrow[lane        ^ swz] = tob((v0-mu)*inv*nw0 + nb0);
            xrow[(lane+64)   ^ swz] = tob((v1-mu)*inv*nw1 + nb1);
            xrow[(lane+128)  ^ swz] = tob((v2-mu)*inv*nw2 + nb2);
        }
    }
    __syncthreads();

    int sw = (li16 & 7) << 3;
    f32x4 acc2[3][4];                       // [nt][rowset], persistent
    #pragma unroll
    for (int j = 0; j < 3; ++j)
        #pragma unroll
        for (int m = 0; m < 4; ++m)
            acc2[j][m] = (f32x4){0.f,0.f,0.f,0.f};

    #pragma unroll 1
    for (int pass = 0; pass < 4; ++pass){
        // ---- FC1: 192 cols this pass; wave owns 3 j, processed SEQUENTIALLY ----
        #pragma unroll
        for (int j = 0; j < 3; ++j){
            int cl  = (wv*3 + j)*16 + li16;        // 0..191
            int col = pass*192 + cl;
            f32x4 a1[4];
            #pragma unroll
            for (int m = 0; m < 4; ++m) a1[m] = (f32x4){0.f,0.f,0.f,0.f};
            #pragma unroll
            for (int kc = 0; kc < 6; ++kc){
                bf16x8v bfr = ldfrag(w1 + (size_t)col*CC + kc*32 + quad*8);
                #pragma unroll
                for (int m = 0; m < 4; ++m){
                    bf16x8v af = ldfrag(xin + (m*16 + li16)*192 + ((kc*32 + quad*8) ^ sw));
                    a1[m] = __builtin_amdgcn_mfma_f32_16x16x32_bf16(af, bfr, a1[m], 0, 0, 0);
                }
            }
            float bb = tof(b1[col]);
            #pragma unroll
            for (int m = 0; m < 4; ++m){
                #pragma unroll
                for (int r = 0; r < 4; ++r){
                    int row = m*16 + quad*4 + r;
                    h1p[row*192 + (cl ^ ((row&7)<<3))] = tob(fast_gelu(a1[m][r] + bb));
                }
            }
        }
        __syncthreads();        // h1 pass-tile ready
        // ---- FC2 partial accumulate: K-slice = 192 (6 kc), af hoisted ----
        #pragma unroll
        for (int kc = 0; kc < 6; ++kc){
            bf16x8v af[4];
            #pragma unroll
            for (int m = 0; m < 4; ++m)
                af[m] = ldfrag(h1p + (m*16 + li16)*192 + ((kc*32 + quad*8) ^ sw));
            int kg = pass*6 + kc;
            #pragma unroll
            for (int j = 0; j < 3; ++j){
                int col = wv*48 + j*16 + li16;
                bf16x8v bfr = ldfrag(w2 + (size_t)col*768 + kg*32 + quad*8);
                #pragma unroll
                for (int m = 0; m < 4; ++m)
                    acc2[j][m] = __builtin_amdgcn_mfma_f32_16x16x32_bf16(af[m], bfr, acc2[j][m], 0, 0, 0);
            }
        }
        __syncthreads();        // FC2 reads done before next pass overwrites h1p
    }

    // ---- writeout: residual; final layer writes converted output ----
    int wout = (outp != nullptr);
    int fl = wout ? *flag : 0;
    #pragma unroll
    for (int j = 0; j < 3; ++j){
        int col = wv*48 + j*16 + li16;
        float bias = tof(b2[col]);
        #pragma unroll
        for (int m = 0; m < 4; ++m){
            #pragma unroll
            for (int r = 0; r < 4; ++r){
                size_t idx = (row0 + m*16 + quad*4 + r)*CC + col;
                float v = xload(&X[idx]) + acc2[j][m][r] + bias;
                if (wout){
                    if (fl) ((bf16*)outp)[idx] = tob(v);
                    else    ((float*)outp)[idx] = v;
                } else {
                    xstore(&X[idx], v);
                }
            }
        }
    }
}

// ---------- driver ----------
template<typename XT>
static void run_pipeline(const bf16* wb, const void* xin0, int* flag,
                         XT* X, bf16* Hwin, bf16* AOut, void* out,
                         hipStream_t stream){
    for (int i = 0; i < 2; ++i){
        int shift = i ? (WSS/2) : 0;
        const void* src = (i == 0) ? xin0 : (const void*)X;
        int dynsrc = (i == 0) ? 1 : 0;
        k_ln_part<XT><<<ROWS/4, 256, 0, stream>>>(src, dynsrc, flag,
                wb+OFF_N1W + i*CC, wb+OFF_N1B + i*CC, Hwin, shift);
        k_attn<<<BB*NWIN, 512, 0, stream>>>(Hwin,
                wb+OFF_QKVW + (size_t)i*3*CC*CC, wb+OFF_QKVB + (size_t)i*3*CC,
                wb+OFF_RPB + (size_t)i*169*NHH, AOut, i);
        k_proj_res<XT><<<ROWS/32, 256, 0, stream>>>(AOut,
                wb+OFF_PROJW + (size_t)i*CC*CC, wb+OFF_PROJB + i*CC,
                src, dynsrc, flag, X, shift);
        k_mlp<XT><<<ROWS/64, 256, 0, stream>>>(X,
                wb+OFF_N2W + i*CC, wb+OFF_N2B + i*CC,
                wb+OFF_F1W + (size_t)i*4*CC*CC, wb+OFF_F1B + (size_t)i*4*CC,
                wb+OFF_F2W + (size_t)i*CC*4*CC, wb+OFF_F2B + i*CC,
                (i == 1) ? out : nullptr, flag);
    }
}

extern "C" void kernel_launch(void* const* d_in, const int* in_sizes, int n_in,
                              void* d_out, int out_size, void* d_ws, size_t ws_size,
                              hipStream_t stream){
    char* p = (char*)d_ws;
    int*  flag = (int*)p;
    bf16* wb   = (bf16*)(p + 16);
    char* q    = p + 16 + (2u<<20);

    k_detect<<<1, 64, 0, stream>>>((const unsigned short*)d_in[1], flag);

    static const int widx[13] = {1,2,3,4,5,6,7,8,9,10,11,12,13};
    static const int woff[13] = {OFF_N1W,OFF_N1B,OFF_QKVW,OFF_QKVB,OFF_RPB,
                                 OFF_PROJW,OFF_PROJB,OFF_N2W,OFF_N2B,
                                 OFF_F1W,OFF_F1B,OFF_F2W,OFF_F2B};
    static const int wsz[13]  = {384,384,221184,1152,2028,73728,384,384,384,
                                 294912,1536,294912,384};
    for (int k = 0; k < 13; ++k)
        k_canon<<<(wsz[k]+255)/256, 256, 0, stream>>>(d_in[widx[k]], wb+woff[k],
                                                      wsz[k], flag);

    size_t needF32 = 16 + (2u<<20) + TOT*4 + TOT*2 + TOT*2;
    if (ws_size >= needF32){
        float* X   = (float*)q;       q += TOT*4;
        bf16* Hwin = (bf16*)q;        q += TOT*2;
        bf16* AOut = (bf16*)q;
        run_pipeline<float>(wb, d_in[0], flag, X, Hwin, AOut, d_out, stream);
    } else {
        bf16* X    = (bf16*)q;        q += TOT*2;
        bf16* Hwin = (bf16*)q;        q += TOT*2;
        bf16* AOut = (bf16*)q;
        run_pipeline<bf16>(wb, d_in[0], flag, X, Hwin, AOut, d_out, stream);
    }
}

// Round 10
// 1090.450 us; speedup vs baseline: 1.1502x; 1.0388x over previous
//
#include <hip/hip_runtime.h>
#include <hip/hip_bf16.h>
#include <math.h>

typedef __hip_bfloat16 bf16;

#define BB    32
#define HH    56
#define WWI   56
#define CC    192
#define NHH   6
#define WSS   7
#define NN    49
#define NWIN  64
#define HDD   32
#define LL    (HH*WWI)
#define ROWS  (BB*NWIN*NN)         // 100352
#define TOT   ((size_t)ROWS*CC)    // 19267584
#define SCALEQ 0.17677669529663687f

// canonical bf16 weight buffer element offsets
#define OFF_N1W   0
#define OFF_N1B   384
#define OFF_QKVW  768
#define OFF_QKVB  221952
#define OFF_RPB   223104
#define OFF_PROJW 225132
#define OFF_PROJB 298860
#define OFF_N2W   299244
#define OFF_N2B   299628
#define OFF_F1W   300012
#define OFF_F1B   594924
#define OFF_F2W   596460
#define OFF_F2B   891372

typedef __bf16 bf16x8v __attribute__((ext_vector_type(8)));
typedef float  f32x4   __attribute__((ext_vector_type(4)));

__device__ __forceinline__ float tof(bf16 v){ return __bfloat162float(v); }
__device__ __forceinline__ bf16  tob(float v){ return __float2bfloat16(v); }
__device__ __forceinline__ float xload(const float* p){ return *p; }
__device__ __forceinline__ float xload(const bf16*  p){ return tof(*p); }
__device__ __forceinline__ void  xstore(float* p, float v){ *p = v; }
__device__ __forceinline__ void  xstore(bf16*  p, float v){ *p = tob(v); }

__device__ __forceinline__ bf16x8v ldfrag(const bf16* p){
    return *(const bf16x8v*)p;
}
__device__ __forceinline__ unsigned short bfbits(float v){
    bf16 b = tob(v);
    return __builtin_bit_cast(unsigned short, b);
}
__device__ __forceinline__ bf16 mkbf(unsigned short u){
    return __builtin_bit_cast(bf16, u);
}

// dynamic-dtype load: dynf<0 -> typed XT; dynf==0 -> float; dynf==1 -> bf16
template<typename XT>
__device__ __forceinline__ float ldx(const void* p, size_t i, int dynf){
    if (dynf < 0) return xload(((const XT*)p) + i);
    return dynf ? tof(((const bf16*)p)[i]) : ((const float*)p)[i];
}

// A&S 7.1.26 erf, |eps| <= 1.5e-7; gelu exact form
__device__ __forceinline__ float fast_gelu(float x){
    float u = fabsf(x) * 0.70710678118f;
    float t = __builtin_amdgcn_rcpf(1.f + 0.3275911f*u);
    float p = t*(0.254829592f + t*(-0.284496736f + t*(1.421413741f +
              t*(-1.453152027f + t*1.061405429f))));
    float e = __expf(-u*u);
    float erfu = 1.f - p*e;
    float s = copysignf(erfu, x);
    return 0.5f*x*(1.f + s);
}

// ---------- dtype detect ----------
__global__ void k_detect(const unsigned short* __restrict__ w, int* __restrict__ flag){
    if (blockIdx.x == 0 && threadIdx.x == 0){
        int cnt = 0;
        for (int k = 0; k < 16; ++k){
            unsigned short u = w[2*k];
            if (u >= 0x3E00 && u <= 0x4100) ++cnt;
        }
        *flag = (cnt >= 8) ? 1 : 0;
    }
}

__global__ void k_canon(const void* __restrict__ src, bf16* __restrict__ dst,
                        int n, const int* __restrict__ flag){
    int i = blockIdx.x * blockDim.x + threadIdx.x;
    if (i >= n) return;
    if (*flag) dst[i] = ((const bf16*)src)[i];
    else       dst[i] = tob(((const float*)src)[i]);
}

// ---------- final output convert, 8 elems/thread, 16B stores ----------
template<typename XT>
__global__ __launch_bounds__(256) void k_out(const XT* __restrict__ X,
        void* __restrict__ out, const int* __restrict__ flag){
    size_t i = ((size_t)blockIdx.x * 256 + threadIdx.x) * 8;
    if (i >= TOT) return;
    float v[8];
    if constexpr (sizeof(XT) == 4){
        f32x4 a = *(const f32x4*)((const float*)X + i);
        f32x4 b = *(const f32x4*)((const float*)X + i + 4);
        #pragma unroll
        for (int e = 0; e < 4; ++e){ v[e] = a[e]; v[4+e] = b[e]; }
    } else {
        bf16x8v a = ldfrag((const bf16*)X + i);
        #pragma unroll
        for (int e = 0; e < 8; ++e) v[e] = tof(mkbf(__builtin_bit_cast(unsigned short, a[e])));
    }
    if (*flag){
        bf16x8v o;
        #pragma unroll
        for (int e = 0; e < 8; ++e) o[e] = __builtin_bit_cast(__bf16, bfbits(v[e]));
        *(bf16x8v*)((bf16*)out + i) = o;
    } else {
        f32x4 o0, o1;
        #pragma unroll
        for (int e = 0; e < 4; ++e){ o0[e] = v[e]; o1[e] = v[4+e]; }
        *(f32x4*)((float*)out + i)     = o0;
        *(f32x4*)((float*)out + i + 4) = o1;
    }
}

// ---------- LN1 + shift + window partition : wave-per-row, no LDS ----------
// src: layer0 = raw input (dtype via flag), layer1 = X (typed XT). Read-only.
template<typename XT>
__global__ __launch_bounds__(256) void k_ln_part(const void* __restrict__ src,
        int dynsrc, const int* __restrict__ flag,
        const bf16* __restrict__ w, const bf16* __restrict__ bsh,
        bf16* __restrict__ Hwin, int shift){
    int dynf = dynsrc ? flag[0] : -1;
    int wv = threadIdx.x >> 6, lane = threadIdx.x & 63;
    int row = blockIdx.x*4 + wv;                 // ROWS % 4 == 0
    int b   = row / (NWIN*NN);
    int win = (row / NN) % NWIN;
    int n   = row % NN;
    int wh = win >> 3, ww = win & 7;
    int iy = n / WSS, ix = n % WSS;
    int sy = (wh*WSS + iy + shift) % HH;
    int sx = (ww*WSS + ix + shift) % WWI;
    size_t base = ((size_t)(b*LL + sy*WWI + sx))*CC;
    float v0 = ldx<XT>(src, base + lane,       dynf);
    float v1 = ldx<XT>(src, base + lane + 64,  dynf);
    float v2 = ldx<XT>(src, base + lane + 128, dynf);
    float sm  = v0+v1+v2;
    float sm2 = v0*v0+v1*v1+v2*v2;
    #pragma unroll
    for (int st = 1; st < 64; st <<= 1){
        sm  += __shfl_xor(sm,  st);
        sm2 += __shfl_xor(sm2, st);
    }
    float mu  = sm * (1.f/CC);
    float inv = rsqrtf(sm2*(1.f/CC) - mu*mu + 1e-5f);
    bf16* dst = Hwin + (size_t)row*CC;
    dst[lane]     = tob((v0-mu)*inv*tof(w[lane])     + tof(bsh[lane]));
    dst[lane+64]  = tob((v1-mu)*inv*tof(w[lane+64])  + tof(bsh[lane+64]));
    dst[lane+128] = tob((v2-mu)*inv*tof(w[lane+128]) + tof(bsh[lane+128]));
}

// ---------- window attention, MFMA, 4-barrier structure ----------
__device__ __forceinline__ int mt0(int i){ return (i < 3) ? i*16 : 33; }

__global__ __launch_bounds__(512, 4) void k_attn(const bf16* __restrict__ Hwin,
        const bf16* __restrict__ qkvw, const bf16* __restrict__ qkvb,
        const bf16* __restrict__ rpb, bf16* __restrict__ AOut, int masked){
    __shared__ bf16 smem[31104];                 // 62208 B
    bf16* qls = smem;
    bf16* kls = smem + 9408;
    bf16* vT  = smem + 18816;
    bf16* Pls = smem;                            // alias q+k after barrier #2

    int t = threadIdx.x;
    int win  = blockIdx.x;
    int winl = win & (NWIN-1);
    int wh = winl >> 3, ww = winl & 7;
    int wv = t >> 6, lane = t & 63;
    int li16 = lane & 15, quad = lane >> 4;

    for (int idx = t; idx < 192*15; idx += 512){
        int d = idx / 15, tokp = 49 + idx % 15;
        vT[d*64 + (tokp ^ ((d&7)<<3))] = tob(0.f);
    }

    // ---- phase Q: QKV for ALL heads, one long phase ----
    {
        int p = wv & 1, c = wv >> 1;
        int m0a = mt0(2*p), m0b = mt0(2*p+1);
        const bf16* hg = Hwin + (size_t)win*NN*CC;
        bf16x8v afa[6], afb[6];
        #pragma unroll
        for (int kc = 0; kc < 6; ++kc){
            afa[kc] = ldfrag(hg + (m0a+li16)*CC + kc*32 + quad*8);
            afb[kc] = ldfrag(hg + (m0b+li16)*CC + kc*32 + quad*8);
        }
        #pragma unroll 3
        for (int j = 0; j < 9; ++j){
            int nt = c + 4*j;
            int col = nt*16 + li16;
            f32x4 acc0 = {0.f,0.f,0.f,0.f}, acc1 = {0.f,0.f,0.f,0.f};
            #pragma unroll
            for (int kc = 0; kc < 6; ++kc){
                bf16x8v bfr = ldfrag(qkvw + (size_t)col*CC + kc*32 + quad*8);
                acc0 = __builtin_amdgcn_mfma_f32_16x16x32_bf16(afa[kc], bfr, acc0, 0, 0, 0);
                acc1 = __builtin_amdgcn_mfma_f32_16x16x32_bf16(afb[kc], bfr, acc1, 0, 0, 0);
            }
            float bias = tof(qkvb[col]);
            int m  = col / CC;
            int cm = col - m*CC;
            #pragma unroll
            for (int r = 0; r < 4; ++r){
                int rowA = m0a + quad*4 + r;
                int rowB = m0b + quad*4 + r;
                float v0 = acc0[r] + bias, v1 = acc1[r] + bias;
                if (m == 0){
                    qls[rowA*CC + (cm ^ ((rowA&7)<<3))] = tob(v0*SCALEQ);
                    qls[rowB*CC + (cm ^ ((rowB&7)<<3))] = tob(v1*SCALEQ);
                } else if (m == 1){
                    kls[rowA*CC + (cm ^ ((rowA&7)<<3))] = tob(v0);
                    kls[rowB*CC + (cm ^ ((rowB&7)<<3))] = tob(v1);
                } else {
                    vT[cm*64 + (rowA ^ ((cm&7)<<3))] = tob(v0);
                    vT[cm*64 + (rowB ^ ((cm&7)<<3))] = tob(v1);
                }
            }
        }
    }
    __syncthreads();   // #1

    unsigned int pk[3][8];
    #pragma unroll
    for (int j = 0; j < 3; ++j){
        int id = wv + 8*j;
        int mt = id & 3, h = id >> 2;
        int m0 = mt0(mt);
        int rowq = m0 + li16;
        bf16x8v afr = ldfrag(qls + rowq*CC + ((h*32 + quad*8) ^ ((rowq&7)<<3)));
        f32x4 s[4];
        #pragma unroll
        for (int nt = 0; nt < 4; ++nt){
            int rowk = nt*16 + li16;
            bf16x8v bfr = ldfrag(kls + rowk*CC + ((h*32 + quad*8) ^ ((rowk&7)<<3)));
            f32x4 z = {0.f,0.f,0.f,0.f};
            s[nt] = __builtin_amdgcn_mfma_f32_16x16x32_bf16(afr, bfr, z, 0, 0, 0);
        }
        #pragma unroll
        for (int nt = 0; nt < 4; ++nt){
            int jj = nt*16 + li16;
            int valid = (jj < NN);
            int jc = valid ? jj : 48;
            int yj = (jc*37) >> 8, xj = jc - 7*yj;
            int lj = 0;
            if (masked){
                int ayj = wh*WSS + yj, axj = ww*WSS + xj;
                lj = ((ayj<49)?0:(ayj<53)?1:2)*3 + ((axj<49)?0:(axj<53)?1:2);
            }
            #pragma unroll
            for (int r = 0; r < 4; ++r){
                int i = m0 + quad*4 + r;
                int yi = (i*37) >> 8, xi = i - 7*yi;
                int ridx = (yi - yj + 6)*13 + (xi - xj + 6);
                float v = s[nt][r] + tof(rpb[ridx*NHH + h]);
                if (masked){
                    int ayi = wh*WSS + yi, axi = ww*WSS + xi;
                    int li = ((ayi<49)?0:(ayi<53)?1:2)*3 + ((axi<49)?0:(axi<53)?1:2);
                    if (li != lj) v -= 100.f;
                }
                s[nt][r] = valid ? v : -1e30f;
            }
        }
        float mx[4], sm[4];
        #pragma unroll
        for (int r = 0; r < 4; ++r)
            mx[r] = fmaxf(fmaxf(s[0][r], s[1][r]), fmaxf(s[2][r], s[3][r]));
        #pragma unroll
        for (int st = 1; st < 16; st <<= 1){
            #pragma unroll
            for (int r = 0; r < 4; ++r) mx[r] = fmaxf(mx[r], __shfl_xor(mx[r], st));
        }
        #pragma unroll
        for (int nt = 0; nt < 4; ++nt){
            #pragma unroll
            for (int r = 0; r < 4; ++r) s[nt][r] = __expf(s[nt][r] - mx[r]);
        }
        #pragma unroll
        for (int r = 0; r < 4; ++r) sm[r] = (s[0][r]+s[1][r]) + (s[2][r]+s[3][r]);
        #pragma unroll
        for (int st = 1; st < 16; st <<= 1){
            #pragma unroll
            for (int r = 0; r < 4; ++r) sm[r] += __shfl_xor(sm[r], st);
        }
        #pragma unroll
        for (int r = 0; r < 4; ++r) sm[r] = 1.f / sm[r];
        #pragma unroll
        for (int nt = 0; nt < 4; ++nt){
            #pragma unroll
            for (int rr = 0; rr < 2; ++rr){
                unsigned int u0 = bfbits(s[nt][2*rr]   * sm[2*rr]);
                unsigned int u1 = bfbits(s[nt][2*rr+1] * sm[2*rr+1]);
                pk[j][nt*2+rr] = (u1 << 16) | u0;
            }
        }
    }
    __syncthreads();  // #2

    #pragma unroll
    for (int j = 0; j < 3; ++j){
        int id = wv + 8*j;
        int m0 = mt0(id & 3), h = id >> 2;
        #pragma unroll
        for (int nt = 0; nt < 4; ++nt){
            int jj = nt*16 + li16;
            #pragma unroll
            for (int rr = 0; rr < 2; ++rr){
                unsigned int u = pk[j][nt*2+rr];
                int tok0 = m0 + quad*4 + 2*rr;
                int tok1 = tok0 + 1;
                Pls[(h*NN + tok0)*64 + (jj ^ ((tok0&7)<<3))] = mkbf((unsigned short)(u & 0xffff));
                Pls[(h*NN + tok1)*64 + (jj ^ ((tok1&7)<<3))] = mkbf((unsigned short)(u >> 16));
            }
        }
    }
    __syncthreads();  // #3

    {
        int mt = wv & 3, nto = wv >> 2;
        int m0 = mt0(mt), n0 = nto*16;
        #pragma unroll
        for (int h = 0; h < NHH; ++h){
            f32x4 acc = {0.f,0.f,0.f,0.f};
            #pragma unroll
            for (int kc = 0; kc < 2; ++kc){
                int rowp = m0 + li16;
                bf16x8v afr = ldfrag(Pls + (h*NN + rowp)*64 + ((kc*32 + quad*8) ^ ((rowp&7)<<3)));
                int rowv = h*HDD + n0 + li16;
                bf16x8v bfr = ldfrag(vT + rowv*64 + ((kc*32 + quad*8) ^ ((rowv&7)<<3)));
                acc = __builtin_amdgcn_mfma_f32_16x16x32_bf16(afr, bfr, acc, 0, 0, 0);
            }
            #pragma unroll
            for (int r = 0; r < 4; ++r){
                int tok = m0 + quad*4 + r;
                AOut[(size_t)win*NN*CC + tok*CC + h*HDD + n0 + li16] = tob(acc[r]);
            }
        }
    }
}

// ---------- proj (MFMA) + window reverse + roll-by-WS bug + residual ----------
// 32-row blocks. Residual: layer0 reads raw input via rsrc (DISTINCT buffer);
// layer1 reads through the X pointer itself (rsrc aliases X and is then never
// dereferenced -> no restrict UB).
#define AS_STRIDE 200
template<typename XT>
__global__ __launch_bounds__(256) void k_proj_res(const bf16* __restrict__ AOut,
        const bf16* __restrict__ pw, const bf16* __restrict__ pb,
        const void* rsrc, int dynsrc, const int* __restrict__ flag,
        XT* __restrict__ X, int shift){
    __shared__ bf16 as[32*AS_STRIDE];
    int fl = dynsrc ? flag[0] : 0;
    int t = threadIdx.x;
    int row0 = blockIdx.x * 32;
    for (int idx = t; idx < 32*24; idx += 256){
        int r = idx / 24, c8 = idx % 24;
        *(bf16x8v*)(as + r*AS_STRIDE + c8*8) = ldfrag(AOut + (size_t)(row0 + r)*CC + c8*8);
    }
    __syncthreads();
    int wv = t >> 6, lane = t & 63;
    int li16 = lane & 15, quad = lane >> 4;
    int roll = (shift > 0) ? WSS : 0;
    for (int nt = 0; nt < 3; ++nt){
        int n0 = wv*48 + nt*16;
        int col = n0 + li16;
        bf16x8v bfr[6];
        #pragma unroll
        for (int kc = 0; kc < 6; ++kc)
            bfr[kc] = ldfrag(pw + (size_t)col*CC + kc*32 + quad*8);
        float bias = tof(pb[col]);
        for (int mt = 0; mt < 2; ++mt){
            int m0 = mt*16;
            f32x4 acc = {0.f,0.f,0.f,0.f};
            #pragma unroll
            for (int kc = 0; kc < 6; ++kc){
                bf16x8v afr = ldfrag(as + (m0 + li16)*AS_STRIDE + kc*32 + quad*8);
                acc = __builtin_amdgcn_mfma_f32_16x16x32_bf16(afr, bfr[kc], acc, 0, 0, 0);
            }
            #pragma unroll
            for (int r = 0; r < 4; ++r){
                int grow = row0 + m0 + quad*4 + r;
                int b   = grow / (NWIN*NN);
                int rem = grow % (NWIN*NN);
                int win = rem / NN;
                int n   = rem % NN;
                int wh = win >> 3, ww = win & 7;
                int iy = n / WSS, ix = n % WSS;
                int y = (wh*WSS + iy + roll) % HH;
                int x = (ww*WSS + ix + roll) % WWI;
                size_t idx = ((size_t)(b*LL + y*WWI + x))*CC + col;
                float res;
                if (dynsrc)
                    res = fl ? tof(((const bf16*)rsrc)[idx])
                             : ((const float*)rsrc)[idx];
                else
                    res = xload(&X[idx]);
                xstore(&X[idx], res + acc[r] + bias);
            }
        }
    }
}

// ---------- LN2 + FC1(MFMA) + GELU + FC2(MFMA) + residual ----------
// ROUND-4 PROVEN CONFIG (225us), restored VERBATIM (r9's fused-out epilogue
// cost +47us/dispatch): M=64, 4 passes x 192 cols, 256 thr, (256,3).
// FC1 j-sequential (a1[4]=16 regs live next to acc2[3][4]=48 -> no spill).
// LDS: xin 64x192 (24576B) + h1p 64x192 (24576B) = 49152B.
template<typename XT>
__global__ __launch_bounds__(256, 3) void k_mlp(XT* __restrict__ X,
        const bf16* __restrict__ n2w, const bf16* __restrict__ n2b,
        const bf16* __restrict__ w1, const bf16* __restrict__ b1,
        const bf16* __restrict__ w2, const bf16* __restrict__ b2){
    __shared__ bf16 xin[64*192];
    __shared__ bf16 h1p[64*192];
    int t = threadIdx.x;
    int wv = t >> 6, lane = t & 63;
    int li16 = lane & 15, quad = lane >> 4;
    size_t row0 = (size_t)blockIdx.x * 64;

    // ---- LN2: wave-per-row, 16 rows per wave, no barriers ----
    {
        float nw0 = tof(n2w[lane]), nw1 = tof(n2w[lane+64]), nw2 = tof(n2w[lane+128]);
        float nb0 = tof(n2b[lane]), nb1 = tof(n2b[lane+64]), nb2 = tof(n2b[lane+128]);
        #pragma unroll 4
        for (int i = 0; i < 16; ++i){
            int r = wv*16 + i;
            const XT* xr = X + (row0 + r)*CC;
            float v0 = xload(&xr[lane]);
            float v1 = xload(&xr[lane+64]);
            float v2 = xload(&xr[lane+128]);
            float sm  = v0+v1+v2;
            float sm2 = v0*v0+v1*v1+v2*v2;
            #pragma unroll
            for (int st = 1; st < 64; st <<= 1){
                sm  += __shfl_xor(sm,  st);
                sm2 += __shfl_xor(sm2, st);
            }
            float mu  = sm * (1.f/CC);
            float inv = rsqrtf(sm2*(1.f/CC) - mu*mu + 1e-5f);
            int swz = (r&7)<<3;
            bf16* xrow = xin + r*192;
            xrow[lane        ^ swz] = tob((v0-mu)*inv*nw0 + nb0);
            xrow[(lane+64)   ^ swz] = tob((v1-mu)*inv*nw1 + nb1);
            xrow[(lane+128)  ^ swz] = tob((v2-mu)*inv*nw2 + nb2);
        }
    }
    __syncthreads();

    int sw = (li16 & 7) << 3;
    f32x4 acc2[3][4];                       // [nt][rowset], persistent
    #pragma unroll
    for (int j = 0; j < 3; ++j)
        #pragma unroll
        for (int m = 0; m < 4; ++m)
            acc2[j][m] = (f32x4){0.f,0.f,0.f,0.f};

    #pragma unroll 1
    for (int pass = 0; pass < 4; ++pass){
        // ---- FC1: 192 cols this pass; wave owns 3 j, processed SEQUENTIALLY ----
        #pragma unroll
        for (int j = 0; j < 3; ++j){
            int cl  = (wv*3 + j)*16 + li16;        // 0..191
            int col = pass*192 + cl;
            f32x4 a1[4];
            #pragma unroll
            for (int m = 0; m < 4; ++m) a1[m] = (f32x4){0.f,0.f,0.f,0.f};
            #pragma unroll
            for (int kc = 0; kc < 6; ++kc){
                bf16x8v bfr = ldfrag(w1 + (size_t)col*CC + kc*32 + quad*8);
                #pragma unroll
                for (int m = 0; m < 4; ++m){
                    bf16x8v af = ldfrag(xin + (m*16 + li16)*192 + ((kc*32 + quad*8) ^ sw));
                    a1[m] = __builtin_amdgcn_mfma_f32_16x16x32_bf16(af, bfr, a1[m], 0, 0, 0);
                }
            }
            float bb = tof(b1[col]);
            #pragma unroll
            for (int m = 0; m < 4; ++m){
                #pragma unroll
                for (int r = 0; r < 4; ++r){
                    int row = m*16 + quad*4 + r;
                    h1p[row*192 + (cl ^ ((row&7)<<3))] = tob(fast_gelu(a1[m][r] + bb));
                }
            }
        }
        __syncthreads();        // h1 pass-tile ready
        // ---- FC2 partial accumulate: K-slice = 192 (6 kc), af hoisted ----
        #pragma unroll
        for (int kc = 0; kc < 6; ++kc){
            bf16x8v af[4];
            #pragma unroll
            for (int m = 0; m < 4; ++m)
                af[m] = ldfrag(h1p + (m*16 + li16)*192 + ((kc*32 + quad*8) ^ sw));
            int kg = pass*6 + kc;
            #pragma unroll
            for (int j = 0; j < 3; ++j){
                int col = wv*48 + j*16 + li16;
                bf16x8v bfr = ldfrag(w2 + (size_t)col*768 + kg*32 + quad*8);
                #pragma unroll
                for (int m = 0; m < 4; ++m)
                    acc2[j][m] = __builtin_amdgcn_mfma_f32_16x16x32_bf16(af[m], bfr, acc2[j][m], 0, 0, 0);
            }
        }
        __syncthreads();        // FC2 reads done before next pass overwrites h1p
    }

    // ---- writeout + residual (always to X; r4 codegen) ----
    #pragma unroll
    for (int j = 0; j < 3; ++j){
        int col = wv*48 + j*16 + li16;
        float bias = tof(b2[col]);
        #pragma unroll
        for (int m = 0; m < 4; ++m){
            #pragma unroll
            for (int r = 0; r < 4; ++r){
                size_t idx = (row0 + m*16 + quad*4 + r)*CC + col;
                xstore(&X[idx], xload(&X[idx]) + acc2[j][m][r] + bias);
            }
        }
    }
}

// ---------- driver ----------
template<typename XT>
static void run_pipeline(const bf16* wb, const void* xin0, int* flag,
                         XT* X, bf16* Hwin, bf16* AOut, void* out,
                         hipStream_t stream){
    for (int i = 0; i < 2; ++i){
        int shift = i ? (WSS/2) : 0;
        const void* src = (i == 0) ? xin0 : (const void*)X;
        int dynsrc = (i == 0) ? 1 : 0;
        k_ln_part<XT><<<ROWS/4, 256, 0, stream>>>(src, dynsrc, flag,
                wb+OFF_N1W + i*CC, wb+OFF_N1B + i*CC, Hwin, shift);
        k_attn<<<BB*NWIN, 512, 0, stream>>>(Hwin,
                wb+OFF_QKVW + (size_t)i*3*CC*CC, wb+OFF_QKVB + (size_t)i*3*CC,
                wb+OFF_RPB + (size_t)i*169*NHH, AOut, i);
        k_proj_res<XT><<<ROWS/32, 256, 0, stream>>>(AOut,
                wb+OFF_PROJW + (size_t)i*CC*CC, wb+OFF_PROJB + i*CC,
                src, dynsrc, flag, X, shift);
        k_mlp<XT><<<ROWS/64, 256, 0, stream>>>(X,
                wb+OFF_N2W + i*CC, wb+OFF_N2B + i*CC,
                wb+OFF_F1W + (size_t)i*4*CC*CC, wb+OFF_F1B + (size_t)i*4*CC,
                wb+OFF_F2W + (size_t)i*CC*4*CC, wb+OFF_F2B + i*CC);
    }
    k_out<XT><<<(int)(TOT/2048), 256, 0, stream>>>(X, out, flag);
}

extern "C" void kernel_launch(void* const* d_in, const int* in_sizes, int n_in,
                              void* d_out, int out_size, void* d_ws, size_t ws_size,
                              hipStream_t stream){
    char* p = (char*)d_ws;
    int*  flag = (int*)p;
    bf16* wb   = (bf16*)(p + 16);
    char* q    = p + 16 + (2u<<20);

    k_detect<<<1, 64, 0, stream>>>((const unsigned short*)d_in[1], flag);

    static const int widx[13] = {1,2,3,4,5,6,7,8,9,10,11,12,13};
    static const int woff[13] = {OFF_N1W,OFF_N1B,OFF_QKVW,OFF_QKVB,OFF_RPB,
                                 OFF_PROJW,OFF_PROJB,OFF_N2W,OFF_N2B,
                                 OFF_F1W,OFF_F1B,OFF_F2W,OFF_F2B};
    static const int wsz[13]  = {384,384,221184,1152,2028,73728,384,384,384,
                                 294912,1536,294912,384};
    for (int k = 0; k < 13; ++k)
        k_canon<<<(wsz[k]+255)/256, 256, 0, stream>>>(d_in[widx[k]], wb+woff[k],
                                                      wsz[k], flag);

    size_t needF32 = 16 + (2u<<20) + TOT*4 + TOT*2 + TOT*2;
    if (ws_size >= needF32){
        float* X   = (float*)q;       q += TOT*4;
        bf16* Hwin = (bf16*)q;        q += TOT*2;
        bf16* AOut = (bf16*)q;
        run_pipeline<float>(wb, d_in[0], flag, X, Hwin, AOut, d_out, stream);
    } else {
        bf16* X    = (bf16*)q;        q += TOT*2;
        bf16* Hwin = (bf16*)q;        q += TOT*2;
        bf16* AOut = (bf16*)q;
        run_pipeline<bf16>(wb, d_in[0], flag, X, Hwin, AOut, d_out, stream);
    }
}

// Round 11
// 1089.603 us; speedup vs baseline: 1.1511x; 1.0008x over previous
//
#include <hip/hip_runtime.h>
#include <hip/hip_bf16.h>
#include <math.h>

typedef __hip_bfloat16 bf16;

#define BB    32
#define HH    56
#define WWI   56
#define CC    192
#define NHH   6
#define WSS   7
#define NN    49
#define NWIN  64
#define HDD   32
#define LL    (HH*WWI)
#define ROWS  (BB*NWIN*NN)         // 100352
#define TOT   ((size_t)ROWS*CC)    // 19267584
#define SCALEQ 0.17677669529663687f

// canonical bf16 weight buffer element offsets
#define OFF_N1W   0
#define OFF_N1B   384
#define OFF_QKVW  768
#define OFF_QKVB  221952
#define OFF_RPB   223104
#define OFF_PROJW 225132
#define OFF_PROJB 298860
#define OFF_N2W   299244
#define OFF_N2B   299628
#define OFF_F1W   300012
#define OFF_F1B   594924
#define OFF_F2W   596460
#define OFF_F2B   891372

typedef __bf16 bf16x8v __attribute__((ext_vector_type(8)));
typedef float  f32x4   __attribute__((ext_vector_type(4)));

__device__ __forceinline__ float tof(bf16 v){ return __bfloat162float(v); }
__device__ __forceinline__ bf16  tob(float v){ return __float2bfloat16(v); }
__device__ __forceinline__ float xload(const float* p){ return *p; }
__device__ __forceinline__ float xload(const bf16*  p){ return tof(*p); }
__device__ __forceinline__ void  xstore(float* p, float v){ *p = v; }
__device__ __forceinline__ void  xstore(bf16*  p, float v){ *p = tob(v); }

__device__ __forceinline__ bf16x8v ldfrag(const bf16* p){
    return *(const bf16x8v*)p;
}
__device__ __forceinline__ unsigned short bfbits(float v){
    bf16 b = tob(v);
    return __builtin_bit_cast(unsigned short, b);
}
__device__ __forceinline__ bf16 mkbf(unsigned short u){
    return __builtin_bit_cast(bf16, u);
}

// dynamic-dtype load: dynf<0 -> typed XT; dynf==0 -> float; dynf==1 -> bf16
template<typename XT>
__device__ __forceinline__ float ldx(const void* p, size_t i, int dynf){
    if (dynf < 0) return xload(((const XT*)p) + i);
    return dynf ? tof(((const bf16*)p)[i]) : ((const float*)p)[i];
}

// A&S 7.1.26 erf, |eps| <= 1.5e-7; gelu exact form
__device__ __forceinline__ float fast_gelu(float x){
    float u = fabsf(x) * 0.70710678118f;
    float t = __builtin_amdgcn_rcpf(1.f + 0.3275911f*u);
    float p = t*(0.254829592f + t*(-0.284496736f + t*(1.421413741f +
              t*(-1.453152027f + t*1.061405429f))));
    float e = __expf(-u*u);
    float erfu = 1.f - p*e;
    float s = copysignf(erfu, x);
    return 0.5f*x*(1.f + s);
}

// ---------- dtype detect ----------
__global__ void k_detect(const unsigned short* __restrict__ w, int* __restrict__ flag){
    if (blockIdx.x == 0 && threadIdx.x == 0){
        int cnt = 0;
        for (int k = 0; k < 16; ++k){
            unsigned short u = w[2*k];
            if (u >= 0x3E00 && u <= 0x4100) ++cnt;
        }
        *flag = (cnt >= 8) ? 1 : 0;
    }
}

__global__ void k_canon(const void* __restrict__ src, bf16* __restrict__ dst,
                        int n, const int* __restrict__ flag){
    int i = blockIdx.x * blockDim.x + threadIdx.x;
    if (i >= n) return;
    if (*flag) dst[i] = ((const bf16*)src)[i];
    else       dst[i] = tob(((const float*)src)[i]);
}

// ---------- final output convert, 8 elems/thread, 16B stores ----------
template<typename XT>
__global__ __launch_bounds__(256) void k_out(const XT* __restrict__ X,
        void* __restrict__ out, const int* __restrict__ flag){
    size_t i = ((size_t)blockIdx.x * 256 + threadIdx.x) * 8;
    if (i >= TOT) return;
    float v[8];
    if constexpr (sizeof(XT) == 4){
        f32x4 a = *(const f32x4*)((const float*)X + i);
        f32x4 b = *(const f32x4*)((const float*)X + i + 4);
        #pragma unroll
        for (int e = 0; e < 4; ++e){ v[e] = a[e]; v[4+e] = b[e]; }
    } else {
        bf16x8v a = ldfrag((const bf16*)X + i);
        #pragma unroll
        for (int e = 0; e < 8; ++e) v[e] = tof(mkbf(__builtin_bit_cast(unsigned short, a[e])));
    }
    if (*flag){
        bf16x8v o;
        #pragma unroll
        for (int e = 0; e < 8; ++e) o[e] = __builtin_bit_cast(__bf16, bfbits(v[e]));
        *(bf16x8v*)((bf16*)out + i) = o;
    } else {
        f32x4 o0, o1;
        #pragma unroll
        for (int e = 0; e < 4; ++e){ o0[e] = v[e]; o1[e] = v[4+e]; }
        *(f32x4*)((float*)out + i)     = o0;
        *(f32x4*)((float*)out + i + 4) = o1;
    }
}

// ---------- LN1 + shift + window partition : wave-per-row, no LDS ----------
// src: layer0 = raw input (dtype via flag), layer1 = X (typed XT). Read-only.
template<typename XT>
__global__ __launch_bounds__(256) void k_ln_part(const void* __restrict__ src,
        int dynsrc, const int* __restrict__ flag,
        const bf16* __restrict__ w, const bf16* __restrict__ bsh,
        bf16* __restrict__ Hwin, int shift){
    int dynf = dynsrc ? flag[0] : -1;
    int wv = threadIdx.x >> 6, lane = threadIdx.x & 63;
    int row = blockIdx.x*4 + wv;                 // ROWS % 4 == 0
    int b   = row / (NWIN*NN);
    int win = (row / NN) % NWIN;
    int n   = row % NN;
    int wh = win >> 3, ww = win & 7;
    int iy = n / WSS, ix = n % WSS;
    int sy = (wh*WSS + iy + shift) % HH;
    int sx = (ww*WSS + ix + shift) % WWI;
    size_t base = ((size_t)(b*LL + sy*WWI + sx))*CC;
    float v0 = ldx<XT>(src, base + lane,       dynf);
    float v1 = ldx<XT>(src, base + lane + 64,  dynf);
    float v2 = ldx<XT>(src, base + lane + 128, dynf);
    float sm  = v0+v1+v2;
    float sm2 = v0*v0+v1*v1+v2*v2;
    #pragma unroll
    for (int st = 1; st < 64; st <<= 1){
        sm  += __shfl_xor(sm,  st);
        sm2 += __shfl_xor(sm2, st);
    }
    float mu  = sm * (1.f/CC);
    float inv = rsqrtf(sm2*(1.f/CC) - mu*mu + 1e-5f);
    bf16* dst = Hwin + (size_t)row*CC;
    dst[lane]     = tob((v0-mu)*inv*tof(w[lane])     + tof(bsh[lane]));
    dst[lane+64]  = tob((v1-mu)*inv*tof(w[lane+64])  + tof(bsh[lane+64]));
    dst[lane+128] = tob((v2-mu)*inv*tof(w[lane+128]) + tof(bsh[lane+128]));
}

// ---------- window attention + PROJ + residual, fused ----------
// Phases: Q(QKV all heads) | S+softmax | P store | PV | O->LDS | proj MFMA +
// window-reverse + roll-by-WS bug + residual RMW on X.
// AOut round-trip eliminated. M-tiles {0,16,32,33} overlap rows 33..47:
// benign for idempotent LDS writes; proj epilogue predicates m0==33 to
// write ONLY tok==48 (avoids double residual-add).
__device__ __forceinline__ int mt0(int i){ return (i < 3) ? i*16 : 33; }

#define OL_ST 200
template<typename XT>
__global__ __launch_bounds__(512, 4) void k_attn(const bf16* __restrict__ Hwin,
        const bf16* __restrict__ qkvw, const bf16* __restrict__ qkvb,
        const bf16* __restrict__ rpb,
        const bf16* __restrict__ pw, const bf16* __restrict__ pb,
        const void* rsrc, int dynsrc, const int* __restrict__ flag,
        XT* __restrict__ X, int masked){
    __shared__ bf16 smem[31104];                 // 62208 B
    bf16* qls = smem;
    bf16* kls = smem + 9408;
    bf16* vT  = smem + 18816;
    bf16* Pls = smem;                            // alias q+k after barrier #2
    bf16* OLs = smem;                            // alias P after barrier #4 (49x200 = 19600 elems)

    int fl = dynsrc ? flag[0] : 0;
    int t = threadIdx.x;
    int win  = blockIdx.x;
    int winl = win & (NWIN-1);
    int wh = winl >> 3, ww = winl & 7;
    int wv = t >> 6, lane = t & 63;
    int li16 = lane & 15, quad = lane >> 4;

    for (int idx = t; idx < 192*15; idx += 512){
        int d = idx / 15, tokp = 49 + idx % 15;
        vT[d*64 + (tokp ^ ((d&7)<<3))] = tob(0.f);
    }

    // ---- phase Q: QKV for ALL heads, one long phase ----
    {
        int p = wv & 1, c = wv >> 1;
        int m0a = mt0(2*p), m0b = mt0(2*p+1);
        const bf16* hg = Hwin + (size_t)win*NN*CC;
        bf16x8v afa[6], afb[6];
        #pragma unroll
        for (int kc = 0; kc < 6; ++kc){
            afa[kc] = ldfrag(hg + (m0a+li16)*CC + kc*32 + quad*8);
            afb[kc] = ldfrag(hg + (m0b+li16)*CC + kc*32 + quad*8);
        }
        #pragma unroll 3
        for (int j = 0; j < 9; ++j){
            int nt = c + 4*j;
            int col = nt*16 + li16;
            f32x4 acc0 = {0.f,0.f,0.f,0.f}, acc1 = {0.f,0.f,0.f,0.f};
            #pragma unroll
            for (int kc = 0; kc < 6; ++kc){
                bf16x8v bfr = ldfrag(qkvw + (size_t)col*CC + kc*32 + quad*8);
                acc0 = __builtin_amdgcn_mfma_f32_16x16x32_bf16(afa[kc], bfr, acc0, 0, 0, 0);
                acc1 = __builtin_amdgcn_mfma_f32_16x16x32_bf16(afb[kc], bfr, acc1, 0, 0, 0);
            }
            float bias = tof(qkvb[col]);
            int m  = col / CC;
            int cm = col - m*CC;
            #pragma unroll
            for (int r = 0; r < 4; ++r){
                int rowA = m0a + quad*4 + r;
                int rowB = m0b + quad*4 + r;
                float v0 = acc0[r] + bias, v1 = acc1[r] + bias;
                if (m == 0){
                    qls[rowA*CC + (cm ^ ((rowA&7)<<3))] = tob(v0*SCALEQ);
                    qls[rowB*CC + (cm ^ ((rowB&7)<<3))] = tob(v1*SCALEQ);
                } else if (m == 1){
                    kls[rowA*CC + (cm ^ ((rowA&7)<<3))] = tob(v0);
                    kls[rowB*CC + (cm ^ ((rowB&7)<<3))] = tob(v1);
                } else {
                    vT[cm*64 + (rowA ^ ((cm&7)<<3))] = tob(v0);
                    vT[cm*64 + (rowB ^ ((cm&7)<<3))] = tob(v1);
                }
            }
        }
    }
    __syncthreads();   // #1

    unsigned int pk[3][8];
    #pragma unroll
    for (int j = 0; j < 3; ++j){
        int id = wv + 8*j;
        int mt = id & 3, h = id >> 2;
        int m0 = mt0(mt);
        int rowq = m0 + li16;
        bf16x8v afr = ldfrag(qls + rowq*CC + ((h*32 + quad*8) ^ ((rowq&7)<<3)));
        f32x4 s[4];
        #pragma unroll
        for (int nt = 0; nt < 4; ++nt){
            int rowk = nt*16 + li16;
            bf16x8v bfr = ldfrag(kls + rowk*CC + ((h*32 + quad*8) ^ ((rowk&7)<<3)));
            f32x4 z = {0.f,0.f,0.f,0.f};
            s[nt] = __builtin_amdgcn_mfma_f32_16x16x32_bf16(afr, bfr, z, 0, 0, 0);
        }
        #pragma unroll
        for (int nt = 0; nt < 4; ++nt){
            int jj = nt*16 + li16;
            int valid = (jj < NN);
            int jc = valid ? jj : 48;
            int yj = (jc*37) >> 8, xj = jc - 7*yj;
            int lj = 0;
            if (masked){
                int ayj = wh*WSS + yj, axj = ww*WSS + xj;
                lj = ((ayj<49)?0:(ayj<53)?1:2)*3 + ((axj<49)?0:(axj<53)?1:2);
            }
            #pragma unroll
            for (int r = 0; r < 4; ++r){
                int i = m0 + quad*4 + r;
                int yi = (i*37) >> 8, xi = i - 7*yi;
                int ridx = (yi - yj + 6)*13 + (xi - xj + 6);
                float v = s[nt][r] + tof(rpb[ridx*NHH + h]);
                if (masked){
                    int ayi = wh*WSS + yi, axi = ww*WSS + xi;
                    int li = ((ayi<49)?0:(ayi<53)?1:2)*3 + ((axi<49)?0:(axi<53)?1:2);
                    if (li != lj) v -= 100.f;
                }
                s[nt][r] = valid ? v : -1e30f;
            }
        }
        float mx[4], sm[4];
        #pragma unroll
        for (int r = 0; r < 4; ++r)
            mx[r] = fmaxf(fmaxf(s[0][r], s[1][r]), fmaxf(s[2][r], s[3][r]));
        #pragma unroll
        for (int st = 1; st < 16; st <<= 1){
            #pragma unroll
            for (int r = 0; r < 4; ++r) mx[r] = fmaxf(mx[r], __shfl_xor(mx[r], st));
        }
        #pragma unroll
        for (int nt = 0; nt < 4; ++nt){
            #pragma unroll
            for (int r = 0; r < 4; ++r) s[nt][r] = __expf(s[nt][r] - mx[r]);
        }
        #pragma unroll
        for (int r = 0; r < 4; ++r) sm[r] = (s[0][r]+s[1][r]) + (s[2][r]+s[3][r]);
        #pragma unroll
        for (int st = 1; st < 16; st <<= 1){
            #pragma unroll
            for (int r = 0; r < 4; ++r) sm[r] += __shfl_xor(sm[r], st);
        }
        #pragma unroll
        for (int r = 0; r < 4; ++r) sm[r] = 1.f / sm[r];
        #pragma unroll
        for (int nt = 0; nt < 4; ++nt){
            #pragma unroll
            for (int rr = 0; rr < 2; ++rr){
                unsigned int u0 = bfbits(s[nt][2*rr]   * sm[2*rr]);
                unsigned int u1 = bfbits(s[nt][2*rr+1] * sm[2*rr+1]);
                pk[j][nt*2+rr] = (u1 << 16) | u0;
            }
        }
    }
    __syncthreads();  // #2

    #pragma unroll
    for (int j = 0; j < 3; ++j){
        int id = wv + 8*j;
        int m0 = mt0(id & 3), h = id >> 2;
        #pragma unroll
        for (int nt = 0; nt < 4; ++nt){
            int jj = nt*16 + li16;
            #pragma unroll
            for (int rr = 0; rr < 2; ++rr){
                unsigned int u = pk[j][nt*2+rr];
                int tok0 = m0 + quad*4 + 2*rr;
                int tok1 = tok0 + 1;
                Pls[(h*NN + tok0)*64 + (jj ^ ((tok0&7)<<3))] = mkbf((unsigned short)(u & 0xffff));
                Pls[(h*NN + tok1)*64 + (jj ^ ((tok1&7)<<3))] = mkbf((unsigned short)(u >> 16));
            }
        }
    }
    __syncthreads();  // #3

    // ---- PV: O kept in registers (6 heads x f32x4) ----
    f32x4 oacc[6];
    {
        int mt = wv & 3, nto = wv >> 2;
        int m0 = mt0(mt), n0 = nto*16;
        #pragma unroll
        for (int h = 0; h < NHH; ++h){
            f32x4 acc = {0.f,0.f,0.f,0.f};
            #pragma unroll
            for (int kc = 0; kc < 2; ++kc){
                int rowp = m0 + li16;
                bf16x8v afr = ldfrag(Pls + (h*NN + rowp)*64 + ((kc*32 + quad*8) ^ ((rowp&7)<<3)));
                int rowv = h*HDD + n0 + li16;
                bf16x8v bfr = ldfrag(vT + rowv*64 + ((kc*32 + quad*8) ^ ((rowv&7)<<3)));
                acc = __builtin_amdgcn_mfma_f32_16x16x32_bf16(afr, bfr, acc, 0, 0, 0);
            }
            oacc[h] = acc;
        }
    }
    __syncthreads();  // #4: all PV reads of Pls/vT complete

    // ---- O -> LDS (stride 200, rows 33..47 written twice w/ identical vals) ----
    {
        int mt = wv & 3, nto = wv >> 2;
        int m0 = mt0(mt), n0 = nto*16;
        #pragma unroll
        for (int h = 0; h < NHH; ++h){
            #pragma unroll
            for (int r = 0; r < 4; ++r){
                int tok = m0 + quad*4 + r;
                OLs[tok*OL_ST + h*HDD + n0 + li16] = tob(oacc[h][r]);
            }
        }
    }
    __syncthreads();  // #5: O visible

    // ---- proj MFMA + window reverse + roll-by-WS bug + residual ----
    {
        int b = win >> 6;
        int roll = masked ? WSS : 0;
        int mthalf = wv >> 2, ntg = wv & 3;
        #pragma unroll
        for (int j = 0; j < 3; ++j){
            int col = (ntg*3 + j)*16 + li16;
            bf16x8v bfr[6];
            #pragma unroll
            for (int kc = 0; kc < 6; ++kc)
                bfr[kc] = ldfrag(pw + (size_t)col*CC + kc*32 + quad*8);
            float bias = tof(pb[col]);
            #pragma unroll
            for (int mtl = 0; mtl < 2; ++mtl){
                int m0 = mt0(mthalf*2 + mtl);
                f32x4 acc = {0.f,0.f,0.f,0.f};
                #pragma unroll
                for (int kc = 0; kc < 6; ++kc){
                    bf16x8v afr = ldfrag(OLs + (m0 + li16)*OL_ST + kc*32 + quad*8);
                    acc = __builtin_amdgcn_mfma_f32_16x16x32_bf16(afr, bfr[kc], acc, 0, 0, 0);
                }
                #pragma unroll
                for (int r = 0; r < 4; ++r){
                    int tok = m0 + quad*4 + r;
                    if (m0 == 33 && tok != 48) continue;   // rows 33..47 owned by m0=32 tile
                    int iy = (tok*37) >> 8, ix = tok - 7*iy;
                    int y = (wh*WSS + iy + roll) % HH;
                    int x = (ww*WSS + ix + roll) % WWI;
                    size_t idx = ((size_t)(b*LL + y*WWI + x))*CC + col;
                    float res;
                    if (dynsrc)
                        res = fl ? tof(((const bf16*)rsrc)[idx])
                                 : ((const float*)rsrc)[idx];
                    else
                        res = xload(&X[idx]);
                    xstore(&X[idx], res + acc[r] + bias);
                }
            }
        }
    }
}

// ---------- LN2 + FC1(MFMA) + GELU + FC2(MFMA) + residual ----------
// ROUND-4 PROVEN CONFIG: M=64, 4 passes x 192 cols, 256 thr, (256,3).
// FC1 j-sequential (a1[4]=16 regs live next to acc2[3][4]=48 -> no spill).
// LDS: xin 64x192 (24576B) + h1p 64x192 (24576B) = 49152B.
template<typename XT>
__global__ __launch_bounds__(256, 3) void k_mlp(XT* __restrict__ X,
        const bf16* __restrict__ n2w, const bf16* __restrict__ n2b,
        const bf16* __restrict__ w1, const bf16* __restrict__ b1,
        const bf16* __restrict__ w2, const bf16* __restrict__ b2){
    __shared__ bf16 xin[64*192];
    __shared__ bf16 h1p[64*192];
    int t = threadIdx.x;
    int wv = t >> 6, lane = t & 63;
    int li16 = lane & 15, quad = lane >> 4;
    size_t row0 = (size_t)blockIdx.x * 64;

    // ---- LN2: wave-per-row, 16 rows per wave, no barriers ----
    {
        float nw0 = tof(n2w[lane]), nw1 = tof(n2w[lane+64]), nw2 = tof(n2w[lane+128]);
        float nb0 = tof(n2b[lane]), nb1 = tof(n2b[lane+64]), nb2 = tof(n2b[lane+128]);
        #pragma unroll 4
        for (int i = 0; i < 16; ++i){
            int r = wv*16 + i;
            const XT* xr = X + (row0 + r)*CC;
            float v0 = xload(&xr[lane]);
            float v1 = xload(&xr[lane+64]);
            float v2 = xload(&xr[lane+128]);
            float sm  = v0+v1+v2;
            float sm2 = v0*v0+v1*v1+v2*v2;
            #pragma unroll
            for (int st = 1; st < 64; st <<= 1){
                sm  += __shfl_xor(sm,  st);
                sm2 += __shfl_xor(sm2, st);
            }
            float mu  = sm * (1.f/CC);
            float inv = rsqrtf(sm2*(1.f/CC) - mu*mu + 1e-5f);
            int swz = (r&7)<<3;
            bf16* xrow = xin + r*192;
            xrow[lane        ^ swz] = tob((v0-mu)*inv*nw0 + nb0);
            xrow[(lane+64)   ^ swz] = tob((v1-mu)*inv*nw1 + nb1);
            xrow[(lane+128)  ^ swz] = tob((v2-mu)*inv*nw2 + nb2);
        }
    }
    __syncthreads();

    int sw = (li16 & 7) << 3;
    f32x4 acc2[3][4];                       // [nt][rowset], persistent
    #pragma unroll
    for (int j = 0; j < 3; ++j)
        #pragma unroll
        for (int m = 0; m < 4; ++m)
            acc2[j][m] = (f32x4){0.f,0.f,0.f,0.f};

    #pragma unroll 1
    for (int pass = 0; pass < 4; ++pass){
        // ---- FC1: 192 cols this pass; wave owns 3 j, processed SEQUENTIALLY ----
        #pragma unroll
        for (int j = 0; j < 3; ++j){
            int cl  = (wv*3 + j)*16 + li16;        // 0..191
            int col = pass*192 + cl;
            f32x4 a1[4];
            #pragma unroll
            for (int m = 0; m < 4; ++m) a1[m] = (f32x4){0.f,0.f,0.f,0.f};
            #pragma unroll
            for (int kc = 0; kc < 6; ++kc){
                bf16x8v bfr = ldfrag(w1 + (size_t)col*CC + kc*32 + quad*8);
                #pragma unroll
                for (int m = 0; m < 4; ++m){
                    bf16x8v af = ldfrag(xin + (m*16 + li16)*192 + ((kc*32 + quad*8) ^ sw));
                    a1[m] = __builtin_amdgcn_mfma_f32_16x16x32_bf16(af, bfr, a1[m], 0, 0, 0);
                }
            }
            float bb = tof(b1[col]);
            #pragma unroll
            for (int m = 0; m < 4; ++m){
                #pragma unroll
                for (int r = 0; r < 4; ++r){
                    int row = m*16 + quad*4 + r;
                    h1p[row*192 + (cl ^ ((row&7)<<3))] = tob(fast_gelu(a1[m][r] + bb));
                }
            }
        }
        __syncthreads();        // h1 pass-tile ready
        // ---- FC2 partial accumulate: K-slice = 192 (6 kc), af hoisted ----
        #pragma unroll
        for (int kc = 0; kc < 6; ++kc){
            bf16x8v af[4];
            #pragma unroll
            for (int m = 0; m < 4; ++m)
                af[m] = ldfrag(h1p + (m*16 + li16)*192 + ((kc*32 + quad*8) ^ sw));
            int kg = pass*6 + kc;
            #pragma unroll
            for (int j = 0; j < 3; ++j){
                int col = wv*48 + j*16 + li16;
                bf16x8v bfr = ldfrag(w2 + (size_t)col*768 + kg*32 + quad*8);
                #pragma unroll
                for (int m = 0; m < 4; ++m)
                    acc2[j][m] = __builtin_amdgcn_mfma_f32_16x16x32_bf16(af[m], bfr, acc2[j][m], 0, 0, 0);
            }
        }
        __syncthreads();        // FC2 reads done before next pass overwrites h1p
    }

    // ---- writeout + residual (always to X; r4 codegen) ----
    #pragma unroll
    for (int j = 0; j < 3; ++j){
        int col = wv*48 + j*16 + li16;
        float bias = tof(b2[col]);
        #pragma unroll
        for (int m = 0; m < 4; ++m){
            #pragma unroll
            for (int r = 0; r < 4; ++r){
                size_t idx = (row0 + m*16 + quad*4 + r)*CC + col;
                xstore(&X[idx], xload(&X[idx]) + acc2[j][m][r] + bias);
            }
        }
    }
}

// ---------- driver ----------
template<typename XT>
static void run_pipeline(const bf16* wb, const void* xin0, int* flag,
                         XT* X, bf16* Hwin, void* out,
                         hipStream_t stream){
    for (int i = 0; i < 2; ++i){
        int shift = i ? (WSS/2) : 0;
        const void* src = (i == 0) ? xin0 : (const void*)X;
        int dynsrc = (i == 0) ? 1 : 0;
        k_ln_part<XT><<<ROWS/4, 256, 0, stream>>>(src, dynsrc, flag,
                wb+OFF_N1W + i*CC, wb+OFF_N1B + i*CC, Hwin, shift);
        k_attn<XT><<<BB*NWIN, 512, 0, stream>>>(Hwin,
                wb+OFF_QKVW + (size_t)i*3*CC*CC, wb+OFF_QKVB + (size_t)i*3*CC,
                wb+OFF_RPB + (size_t)i*169*NHH,
                wb+OFF_PROJW + (size_t)i*CC*CC, wb+OFF_PROJB + i*CC,
                src, dynsrc, flag, X, i);
        k_mlp<XT><<<ROWS/64, 256, 0, stream>>>(X,
                wb+OFF_N2W + i*CC, wb+OFF_N2B + i*CC,
                wb+OFF_F1W + (size_t)i*4*CC*CC, wb+OFF_F1B + (size_t)i*4*CC,
                wb+OFF_F2W + (size_t)i*CC*4*CC, wb+OFF_F2B + i*CC);
    }
    k_out<XT><<<(int)(TOT/2048), 256, 0, stream>>>(X, out, flag);
}

extern "C" void kernel_launch(void* const* d_in, const int* in_sizes, int n_in,
                              void* d_out, int out_size, void* d_ws, size_t ws_size,
                              hipStream_t stream){
    char* p = (char*)d_ws;
    int*  flag = (int*)p;
    bf16* wb   = (bf16*)(p + 16);
    char* q    = p + 16 + (2u<<20);

    k_detect<<<1, 64, 0, stream>>>((const unsigned short*)d_in[1], flag);

    static const int widx[13] = {1,2,3,4,5,6,7,8,9,10,11,12,13};
    static const int woff[13] = {OFF_N1W,OFF_N1B,OFF_QKVW,OFF_QKVB,OFF_RPB,
                                 OFF_PROJW,OFF_PROJB,OFF_N2W,OFF_N2B,
                                 OFF_F1W,OFF_F1B,OFF_F2W,OFF_F2B};
    static const int wsz[13]  = {384,384,221184,1152,2028,73728,384,384,384,
                                 294912,1536,294912,384};
    for (int k = 0; k < 13; ++k)
        k_canon<<<(wsz[k]+255)/256, 256, 0, stream>>>(d_in[widx[k]], wb+woff[k],
                                                      wsz[k], flag);

    size_t needF32 = 16 + (2u<<20) + TOT*4 + TOT*2;
    if (ws_size >= needF32){
        float* X   = (float*)q;       q += TOT*4;
        bf16* Hwin = (bf16*)q;
        run_pipeline<float>(wb, d_in[0], flag, X, Hwin, d_out, stream);
    } else {
        bf16* X    = (bf16*)q;        q += TOT*2;
        bf16* Hwin = (bf16*)q;
        run_pipeline<bf16>(wb, d_in[0], flag, X, Hwin, d_out, stream);
    }
}

// Round 13
// 969.955 us; speedup vs baseline: 1.2931x; 1.1234x over previous
//
#include <hip/hip_runtime.h>
#include <hip/hip_bf16.h>
#include <math.h>

typedef __hip_bfloat16 bf16;

#define BB    32
#define HH    56
#define WWI   56
#define CC    192
#define NHH   6
#define WSS   7
#define NN    49
#define NWIN  64
#define HDD   32
#define LL    (HH*WWI)
#define ROWS  (BB*NWIN*NN)         // 100352
#define TOT   ((size_t)ROWS*CC)    // 19267584
#define SCALEQ 0.17677669529663687f

// canonical bf16 weight buffer element offsets
#define OFF_N1W   0
#define OFF_N1B   384
#define OFF_QKVW  768
#define OFF_QKVB  221952
#define OFF_RPB   223104
#define OFF_PROJW 225132
#define OFF_PROJB 298860
#define OFF_N2W   299244
#define OFF_N2B   299628
#define OFF_F1W   300012
#define OFF_F1B   594924
#define OFF_F2W   596460
#define OFF_F2B   891372

typedef __bf16 bf16x8v __attribute__((ext_vector_type(8)));
typedef float  f32x4   __attribute__((ext_vector_type(4)));

__device__ __forceinline__ float tof(bf16 v){ return __bfloat162float(v); }
__device__ __forceinline__ bf16  tob(float v){ return __float2bfloat16(v); }
__device__ __forceinline__ float xload(const float* p){ return *p; }
__device__ __forceinline__ float xload(const bf16*  p){ return tof(*p); }
__device__ __forceinline__ void  xstore(float* p, float v){ *p = v; }
__device__ __forceinline__ void  xstore(bf16*  p, float v){ *p = tob(v); }

__device__ __forceinline__ bf16x8v ldfrag(const bf16* p){
    return *(const bf16x8v*)p;
}
__device__ __forceinline__ unsigned short bfbits(float v){
    bf16 b = tob(v);
    return __builtin_bit_cast(unsigned short, b);
}
__device__ __forceinline__ bf16 mkbf(unsigned short u){
    return __builtin_bit_cast(bf16, u);
}

// dynamic-dtype load: dynf<0 -> typed XT; dynf==0 -> float; dynf==1 -> bf16
template<typename XT>
__device__ __forceinline__ float ldx(const void* p, size_t i, int dynf){
    if (dynf < 0) return xload(((const XT*)p) + i);
    return dynf ? tof(((const bf16*)p)[i]) : ((const float*)p)[i];
}

// A&S 7.1.26 erf, |eps| <= 1.5e-7; gelu exact form
__device__ __forceinline__ float fast_gelu(float x){
    float u = fabsf(x) * 0.70710678118f;
    float t = __builtin_amdgcn_rcpf(1.f + 0.3275911f*u);
    float p = t*(0.254829592f + t*(-0.284496736f + t*(1.421413741f +
              t*(-1.453152027f + t*1.061405429f))));
    float e = __expf(-u*u);
    float erfu = 1.f - p*e;
    float s = copysignf(erfu, x);
    return 0.5f*x*(1.f + s);
}

// ---------- dtype detect ----------
__global__ void k_detect(const unsigned short* __restrict__ w, int* __restrict__ flag){
    if (blockIdx.x == 0 && threadIdx.x == 0){
        int cnt = 0;
        for (int k = 0; k < 16; ++k){
            unsigned short u = w[2*k];
            if (u >= 0x3E00 && u <= 0x4100) ++cnt;
        }
        *flag = (cnt >= 8) ? 1 : 0;
    }
}

__global__ void k_canon(const void* __restrict__ src, bf16* __restrict__ dst,
                        int n, const int* __restrict__ flag){
    int i = blockIdx.x * blockDim.x + threadIdx.x;
    if (i >= n) return;
    if (*flag) dst[i] = ((const bf16*)src)[i];
    else       dst[i] = tob(((const float*)src)[i]);
}

// ---------- final output convert, 8 elems/thread, 16B stores ----------
template<typename XT>
__global__ __launch_bounds__(256) void k_out(const XT* __restrict__ X,
        void* __restrict__ out, const int* __restrict__ flag){
    size_t i = ((size_t)blockIdx.x * 256 + threadIdx.x) * 8;
    if (i >= TOT) return;
    float v[8];
    if constexpr (sizeof(XT) == 4){
        f32x4 a = *(const f32x4*)((const float*)X + i);
        f32x4 b = *(const f32x4*)((const float*)X + i + 4);
        #pragma unroll
        for (int e = 0; e < 4; ++e){ v[e] = a[e]; v[4+e] = b[e]; }
    } else {
        bf16x8v a = ldfrag((const bf16*)X + i);
        #pragma unroll
        for (int e = 0; e < 8; ++e) v[e] = tof(mkbf(__builtin_bit_cast(unsigned short, a[e])));
    }
    if (*flag){
        bf16x8v o;
        #pragma unroll
        for (int e = 0; e < 8; ++e) o[e] = __builtin_bit_cast(__bf16, bfbits(v[e]));
        *(bf16x8v*)((bf16*)out + i) = o;
    } else {
        f32x4 o0, o1;
        #pragma unroll
        for (int e = 0; e < 4; ++e){ o0[e] = v[e]; o1[e] = v[4+e]; }
        *(f32x4*)((float*)out + i)     = o0;
        *(f32x4*)((float*)out + i + 4) = o1;
    }
}

// ---------- LN1 + shift + window partition : wave-per-row, no LDS ----------
// src: layer0 = raw input (dtype via flag), layer1 = X (typed XT). Read-only.
template<typename XT>
__global__ __launch_bounds__(256) void k_ln_part(const void* __restrict__ src,
        int dynsrc, const int* __restrict__ flag,
        const bf16* __restrict__ w, const bf16* __restrict__ bsh,
        bf16* __restrict__ Hwin, int shift){
    int dynf = dynsrc ? flag[0] : -1;
    int wv = threadIdx.x >> 6, lane = threadIdx.x & 63;
    int row = blockIdx.x*4 + wv;                 // ROWS % 4 == 0
    int b   = row / (NWIN*NN);
    int win = (row / NN) % NWIN;
    int n   = row % NN;
    int wh = win >> 3, ww = win & 7;
    int iy = n / WSS, ix = n % WSS;
    int sy = (wh*WSS + iy + shift) % HH;
    int sx = (ww*WSS + ix + shift) % WWI;
    size_t base = ((size_t)(b*LL + sy*WWI + sx))*CC;
    float v0 = ldx<XT>(src, base + lane,       dynf);
    float v1 = ldx<XT>(src, base + lane + 64,  dynf);
    float v2 = ldx<XT>(src, base + lane + 128, dynf);
    float sm  = v0+v1+v2;
    float sm2 = v0*v0+v1*v1+v2*v2;
    #pragma unroll
    for (int st = 1; st < 64; st <<= 1){
        sm  += __shfl_xor(sm,  st);
        sm2 += __shfl_xor(sm2, st);
    }
    float mu  = sm * (1.f/CC);
    float inv = rsqrtf(sm2*(1.f/CC) - mu*mu + 1e-5f);
    bf16* dst = Hwin + (size_t)row*CC;
    dst[lane]     = tob((v0-mu)*inv*tof(w[lane])     + tof(bsh[lane]));
    dst[lane+64]  = tob((v1-mu)*inv*tof(w[lane+64])  + tof(bsh[lane+64]));
    dst[lane+128] = tob((v2-mu)*inv*tof(w[lane+128]) + tof(bsh[lane+128]));
}

// ---------- window attention + PROJ + residual, fused ----------
// Phases: Q | S+softmax | P | PV | O->LDS | proj->projout LDS | coalesced
// row-wise RMW writeout. Writeout uses ONLY typed pointers with explicit
// dynsrc branches (r8/r12 select-through-void*-alias pattern miscompiled);
// X carries no restrict here.
__device__ __forceinline__ int mt0(int i){ return (i < 3) ? i*16 : 33; }

#define OL_ST 200
template<typename XT>
__global__ __launch_bounds__(512, 4) void k_attn(const bf16* __restrict__ Hwin,
        const bf16* __restrict__ qkvw, const bf16* __restrict__ qkvb,
        const bf16* __restrict__ rpb,
        const bf16* __restrict__ pw, const bf16* __restrict__ pb,
        const void* rsrc, int dynsrc, const int* __restrict__ flag,
        XT* X, int masked){
    __shared__ bf16 smem[32128];                 // 64256 B -> 2 blocks/CU
    bf16* qls  = smem;                           // 49x192 swz
    bf16* kls  = smem + 9408;                    // 49x192 swz
    bf16* vT   = smem + 18816;                   // 192x64 swz
    bf16* rpbl = smem + 31104;                   // 1014 staged rpb
    bf16* Pls  = smem;                           // alias q+k after barrier #2
    bf16* OLs  = smem;                           // alias P after barrier #4 (49x200)
    bf16* projout = smem + 18816;                // alias vT after barrier #5 (49x192)

    int fl = dynsrc ? flag[0] : 0;
    int t = threadIdx.x;
    int win  = blockIdx.x;
    int winl = win & (NWIN-1);
    int wh = winl >> 3, ww = winl & 7;
    int wv = t >> 6, lane = t & 63;
    int li16 = lane & 15, quad = lane >> 4;

    for (int idx = t; idx < 192*15; idx += 512){
        int d = idx / 15, tokp = 49 + idx % 15;
        vT[d*64 + (tokp ^ ((d&7)<<3))] = tob(0.f);
    }
    for (int idx = t; idx < 169*NHH; idx += 512) rpbl[idx] = rpb[idx];

    // ---- phase Q: QKV for ALL heads, one long phase ----
    {
        int p = wv & 1, c = wv >> 1;
        int m0a = mt0(2*p), m0b = mt0(2*p+1);
        const bf16* hg = Hwin + (size_t)win*NN*CC;
        bf16x8v afa[6], afb[6];
        #pragma unroll
        for (int kc = 0; kc < 6; ++kc){
            afa[kc] = ldfrag(hg + (m0a+li16)*CC + kc*32 + quad*8);
            afb[kc] = ldfrag(hg + (m0b+li16)*CC + kc*32 + quad*8);
        }
        #pragma unroll 3
        for (int j = 0; j < 9; ++j){
            int nt = c + 4*j;
            int col = nt*16 + li16;
            f32x4 acc0 = {0.f,0.f,0.f,0.f}, acc1 = {0.f,0.f,0.f,0.f};
            #pragma unroll
            for (int kc = 0; kc < 6; ++kc){
                bf16x8v bfr = ldfrag(qkvw + (size_t)col*CC + kc*32 + quad*8);
                acc0 = __builtin_amdgcn_mfma_f32_16x16x32_bf16(afa[kc], bfr, acc0, 0, 0, 0);
                acc1 = __builtin_amdgcn_mfma_f32_16x16x32_bf16(afb[kc], bfr, acc1, 0, 0, 0);
            }
            float bias = tof(qkvb[col]);
            int m  = col / CC;
            int cm = col - m*CC;
            #pragma unroll
            for (int r = 0; r < 4; ++r){
                int rowA = m0a + quad*4 + r;
                int rowB = m0b + quad*4 + r;
                float v0 = acc0[r] + bias, v1 = acc1[r] + bias;
                if (m == 0){
                    qls[rowA*CC + (cm ^ ((rowA&7)<<3))] = tob(v0*SCALEQ);
                    qls[rowB*CC + (cm ^ ((rowB&7)<<3))] = tob(v1*SCALEQ);
                } else if (m == 1){
                    kls[rowA*CC + (cm ^ ((rowA&7)<<3))] = tob(v0);
                    kls[rowB*CC + (cm ^ ((rowB&7)<<3))] = tob(v1);
                } else {
                    vT[cm*64 + (rowA ^ ((cm&7)<<3))] = tob(v0);
                    vT[cm*64 + (rowB ^ ((cm&7)<<3))] = tob(v1);
                }
            }
        }
    }
    __syncthreads();   // #1

    unsigned int pk[3][8];
    #pragma unroll
    for (int j = 0; j < 3; ++j){
        int id = wv + 8*j;
        int mt = id & 3, h = id >> 2;
        int m0 = mt0(mt);
        int rowq = m0 + li16;
        bf16x8v afr = ldfrag(qls + rowq*CC + ((h*32 + quad*8) ^ ((rowq&7)<<3)));
        f32x4 s[4];
        #pragma unroll
        for (int nt = 0; nt < 4; ++nt){
            int rowk = nt*16 + li16;
            bf16x8v bfr = ldfrag(kls + rowk*CC + ((h*32 + quad*8) ^ ((rowk&7)<<3)));
            f32x4 z = {0.f,0.f,0.f,0.f};
            s[nt] = __builtin_amdgcn_mfma_f32_16x16x32_bf16(afr, bfr, z, 0, 0, 0);
        }
        #pragma unroll
        for (int nt = 0; nt < 4; ++nt){
            int jj = nt*16 + li16;
            int valid = (jj < NN);
            int jc = valid ? jj : 48;
            int yj = (jc*37) >> 8, xj = jc - 7*yj;
            int lj = 0;
            if (masked){
                int ayj = wh*WSS + yj, axj = ww*WSS + xj;
                lj = ((ayj<49)?0:(ayj<53)?1:2)*3 + ((axj<49)?0:(axj<53)?1:2);
            }
            #pragma unroll
            for (int r = 0; r < 4; ++r){
                int i = m0 + quad*4 + r;
                int yi = (i*37) >> 8, xi = i - 7*yi;
                int ridx = (yi - yj + 6)*13 + (xi - xj + 6);
                float v = s[nt][r] + tof(rpbl[ridx*NHH + h]);
                if (masked){
                    int ayi = wh*WSS + yi, axi = ww*WSS + xi;
                    int li = ((ayi<49)?0:(ayi<53)?1:2)*3 + ((axi<49)?0:(axi<53)?1:2);
                    if (li != lj) v -= 100.f;
                }
                s[nt][r] = valid ? v : -1e30f;
            }
        }
        float mx[4], sm[4];
        #pragma unroll
        for (int r = 0; r < 4; ++r)
            mx[r] = fmaxf(fmaxf(s[0][r], s[1][r]), fmaxf(s[2][r], s[3][r]));
        #pragma unroll
        for (int st = 1; st < 16; st <<= 1){
            #pragma unroll
            for (int r = 0; r < 4; ++r) mx[r] = fmaxf(mx[r], __shfl_xor(mx[r], st));
        }
        #pragma unroll
        for (int nt = 0; nt < 4; ++nt){
            #pragma unroll
            for (int r = 0; r < 4; ++r) s[nt][r] = __expf(s[nt][r] - mx[r]);
        }
        #pragma unroll
        for (int r = 0; r < 4; ++r) sm[r] = (s[0][r]+s[1][r]) + (s[2][r]+s[3][r]);
        #pragma unroll
        for (int st = 1; st < 16; st <<= 1){
            #pragma unroll
            for (int r = 0; r < 4; ++r) sm[r] += __shfl_xor(sm[r], st);
        }
        #pragma unroll
        for (int r = 0; r < 4; ++r) sm[r] = 1.f / sm[r];
        #pragma unroll
        for (int nt = 0; nt < 4; ++nt){
            #pragma unroll
            for (int rr = 0; rr < 2; ++rr){
                unsigned int u0 = bfbits(s[nt][2*rr]   * sm[2*rr]);
                unsigned int u1 = bfbits(s[nt][2*rr+1] * sm[2*rr+1]);
                pk[j][nt*2+rr] = (u1 << 16) | u0;
            }
        }
    }
    __syncthreads();  // #2

    #pragma unroll
    for (int j = 0; j < 3; ++j){
        int id = wv + 8*j;
        int m0 = mt0(id & 3), h = id >> 2;
        #pragma unroll
        for (int nt = 0; nt < 4; ++nt){
            int jj = nt*16 + li16;
            #pragma unroll
            for (int rr = 0; rr < 2; ++rr){
                unsigned int u = pk[j][nt*2+rr];
                int tok0 = m0 + quad*4 + 2*rr;
                int tok1 = tok0 + 1;
                Pls[(h*NN + tok0)*64 + (jj ^ ((tok0&7)<<3))] = mkbf((unsigned short)(u & 0xffff));
                Pls[(h*NN + tok1)*64 + (jj ^ ((tok1&7)<<3))] = mkbf((unsigned short)(u >> 16));
            }
        }
    }
    __syncthreads();  // #3

    // ---- PV: O kept in registers (6 heads x f32x4) ----
    f32x4 oacc[6];
    {
        int mt = wv & 3, nto = wv >> 2;
        int m0 = mt0(mt), n0 = nto*16;
        #pragma unroll
        for (int h = 0; h < NHH; ++h){
            f32x4 acc = {0.f,0.f,0.f,0.f};
            #pragma unroll
            for (int kc = 0; kc < 2; ++kc){
                int rowp = m0 + li16;
                bf16x8v afr = ldfrag(Pls + (h*NN + rowp)*64 + ((kc*32 + quad*8) ^ ((rowp&7)<<3)));
                int rowv = h*HDD + n0 + li16;
                bf16x8v bfr = ldfrag(vT + rowv*64 + ((kc*32 + quad*8) ^ ((rowv&7)<<3)));
                acc = __builtin_amdgcn_mfma_f32_16x16x32_bf16(afr, bfr, acc, 0, 0, 0);
            }
            oacc[h] = acc;
        }
    }
    __syncthreads();  // #4: all PV reads of Pls/vT complete

    // ---- O -> LDS (stride 200; rows 33..47 double-written w/ identical vals) ----
    {
        int mt = wv & 3, nto = wv >> 2;
        int m0 = mt0(mt), n0 = nto*16;
        #pragma unroll
        for (int h = 0; h < NHH; ++h){
            #pragma unroll
            for (int r = 0; r < 4; ++r){
                int tok = m0 + quad*4 + r;
                OLs[tok*OL_ST + h*HDD + n0 + li16] = tob(oacc[h][r]);
            }
        }
    }
    __syncthreads();  // #5: O visible

    // ---- proj MFMA -> projout LDS (+bias); duplicates idempotent ----
    {
        int mthalf = wv >> 2, ntg = wv & 3;
        #pragma unroll
        for (int j = 0; j < 3; ++j){
            int col = (ntg*3 + j)*16 + li16;
            bf16x8v bfr[6];
            #pragma unroll
            for (int kc = 0; kc < 6; ++kc)
                bfr[kc] = ldfrag(pw + (size_t)col*CC + kc*32 + quad*8);
            float bias = tof(pb[col]);
            #pragma unroll
            for (int mtl = 0; mtl < 2; ++mtl){
                int m0 = mt0(mthalf*2 + mtl);
                f32x4 acc = {0.f,0.f,0.f,0.f};
                #pragma unroll
                for (int kc = 0; kc < 6; ++kc){
                    bf16x8v afr = ldfrag(OLs + (m0 + li16)*OL_ST + kc*32 + quad*8);
                    acc = __builtin_amdgcn_mfma_f32_16x16x32_bf16(afr, bfr[kc], acc, 0, 0, 0);
                }
                #pragma unroll
                for (int r = 0; r < 4; ++r){
                    int tok = m0 + quad*4 + r;
                    projout[tok*192 + col] = tob(acc[r] + bias);
                }
            }
        }
    }
    __syncthreads();  // #6: projout visible

    // ---- cooperative coalesced RMW writeout: typed pointers, no select ----
    {
        int b = win >> 6;
        int roll = masked ? WSS : 0;
        for (int c = t; c < NN*24; c += 512){
            int tok = c / 24, c8 = c % 24;
            int iy = tok / WSS, ix = tok % WSS;
            int y = (wh*WSS + iy + roll) % HH;
            int x = (ww*WSS + ix + roll) % WWI;
            size_t idx = ((size_t)(b*LL + y*WWI + x))*CC + c8*8;
            float pv[8];
            #pragma unroll
            for (int e = 0; e < 8; ++e) pv[e] = tof(projout[tok*192 + c8*8 + e]);
            if (dynsrc){
                // layer 0: X write-only; residual from DISTINCT raw-input buffer
                float v[8];
                if (fl){
                    const bf16* rp = (const bf16*)rsrc;
                    #pragma unroll
                    for (int e = 0; e < 8; ++e) v[e] = tof(rp[idx + e]);
                } else {
                    const float* rp = (const float*)rsrc;
                    #pragma unroll
                    for (int e = 0; e < 8; ++e) v[e] = rp[idx + e];
                }
                #pragma unroll
                for (int e = 0; e < 8; ++e) xstore(&X[idx + e], v[e] + pv[e]);
            } else {
                // layer 1: read AND write through X only (r9/r11-proven pattern)
                #pragma unroll
                for (int e = 0; e < 8; ++e){
                    float v = xload(&X[idx + e]) + pv[e];
                    xstore(&X[idx + e], v);
                }
            }
        }
    }
}

// ---------- LN2 + FC1(MFMA) + GELU + FC2(MFMA) + residual ----------
// ROUND-4 PROVEN CONFIG: M=64, 4 passes x 192 cols, 256 thr, (256,3).
// FC1 j-sequential (a1[4]=16 regs live next to acc2[3][4]=48 -> no spill).
// LDS: xin 64x192 (24576B) + h1p 64x192 (24576B) = 49152B.
template<typename XT>
__global__ __launch_bounds__(256, 3) void k_mlp(XT* __restrict__ X,
        const bf16* __restrict__ n2w, const bf16* __restrict__ n2b,
        const bf16* __restrict__ w1, const bf16* __restrict__ b1,
        const bf16* __restrict__ w2, const bf16* __restrict__ b2){
    __shared__ bf16 xin[64*192];
    __shared__ bf16 h1p[64*192];
    int t = threadIdx.x;
    int wv = t >> 6, lane = t & 63;
    int li16 = lane & 15, quad = lane >> 4;
    size_t row0 = (size_t)blockIdx.x * 64;

    // ---- LN2: wave-per-row, 16 rows per wave, no barriers ----
    {
        float nw0 = tof(n2w[lane]), nw1 = tof(n2w[lane+64]), nw2 = tof(n2w[lane+128]);
        float nb0 = tof(n2b[lane]), nb1 = tof(n2b[lane+64]), nb2 = tof(n2b[lane+128]);
        #pragma unroll 4
        for (int i = 0; i < 16; ++i){
            int r = wv*16 + i;
            const XT* xr = X + (row0 + r)*CC;
            float v0 = xload(&xr[lane]);
            float v1 = xload(&xr[lane+64]);
            float v2 = xload(&xr[lane+128]);
            float sm  = v0+v1+v2;
            float sm2 = v0*v0+v1*v1+v2*v2;
            #pragma unroll
            for (int st = 1; st < 64; st <<= 1){
                sm  += __shfl_xor(sm,  st);
                sm2 += __shfl_xor(sm2, st);
            }
            float mu  = sm * (1.f/CC);
            float inv = rsqrtf(sm2*(1.f/CC) - mu*mu + 1e-5f);
            int swz = (r&7)<<3;
            bf16* xrow = xin + r*192;
            xrow[lane        ^ swz] = tob((v0-mu)*inv*nw0 + nb0);
            xrow[(lane+64)   ^ swz] = tob((v1-mu)*inv*nw1 + nb1);
            xrow[(lane+128)  ^ swz] = tob((v2-mu)*inv*nw2 + nb2);
        }
    }
    __syncthreads();

    int sw = (li16 & 7) << 3;
    f32x4 acc2[3][4];                       // [nt][rowset], persistent
    #pragma unroll
    for (int j = 0; j < 3; ++j)
        #pragma unroll
        for (int m = 0; m < 4; ++m)
            acc2[j][m] = (f32x4){0.f,0.f,0.f,0.f};

    #pragma unroll 1
    for (int pass = 0; pass < 4; ++pass){
        // ---- FC1: 192 cols this pass; wave owns 3 j, processed SEQUENTIALLY ----
        #pragma unroll
        for (int j = 0; j < 3; ++j){
            int cl  = (wv*3 + j)*16 + li16;        // 0..191
            int col = pass*192 + cl;
            f32x4 a1[4];
            #pragma unroll
            for (int m = 0; m < 4; ++m) a1[m] = (f32x4){0.f,0.f,0.f,0.f};
            #pragma unroll
            for (int kc = 0; kc < 6; ++kc){
                bf16x8v bfr = ldfrag(w1 + (size_t)col*CC + kc*32 + quad*8);
                #pragma unroll
                for (int m = 0; m < 4; ++m){
                    bf16x8v af = ldfrag(xin + (m*16 + li16)*192 + ((kc*32 + quad*8) ^ sw));
                    a1[m] = __builtin_amdgcn_mfma_f32_16x16x32_bf16(af, bfr, a1[m], 0, 0, 0);
                }
            }
            float bb = tof(b1[col]);
            #pragma unroll
            for (int m = 0; m < 4; ++m){
                #pragma unroll
                for (int r = 0; r < 4; ++r){
                    int row = m*16 + quad*4 + r;
                    h1p[row*192 + (cl ^ ((row&7)<<3))] = tob(fast_gelu(a1[m][r] + bb));
                }
            }
        }
        __syncthreads();        // h1 pass-tile ready
        // ---- FC2 partial accumulate: K-slice = 192 (6 kc), af hoisted ----
        #pragma unroll
        for (int kc = 0; kc < 6; ++kc){
            bf16x8v af[4];
            #pragma unroll
            for (int m = 0; m < 4; ++m)
                af[m] = ldfrag(h1p + (m*16 + li16)*192 + ((kc*32 + quad*8) ^ sw));
            int kg = pass*6 + kc;
            #pragma unroll
            for (int j = 0; j < 3; ++j){
                int col = wv*48 + j*16 + li16;
                bf16x8v bfr = ldfrag(w2 + (size_t)col*768 + kg*32 + quad*8);
                #pragma unroll
                for (int m = 0; m < 4; ++m)
                    acc2[j][m] = __builtin_amdgcn_mfma_f32_16x16x32_bf16(af[m], bfr, acc2[j][m], 0, 0, 0);
            }
        }
        __syncthreads();        // FC2 reads done before next pass overwrites h1p
    }

    // ---- writeout + residual (always to X; r4 codegen) ----
    #pragma unroll
    for (int j = 0; j < 3; ++j){
        int col = wv*48 + j*16 + li16;
        float bias = tof(b2[col]);
        #pragma unroll
        for (int m = 0; m < 4; ++m){
            #pragma unroll
            for (int r = 0; r < 4; ++r){
                size_t idx = (row0 + m*16 + quad*4 + r)*CC + col;
                xstore(&X[idx], xload(&X[idx]) + acc2[j][m][r] + bias);
            }
        }
    }
}

// ---------- driver ----------
template<typename XT>
static void run_pipeline(const bf16* wb, const void* xin0, int* flag,
                         XT* X, bf16* Hwin, void* out,
                         hipStream_t stream){
    for (int i = 0; i < 2; ++i){
        int shift = i ? (WSS/2) : 0;
        const void* src = (i == 0) ? xin0 : (const void*)X;
        int dynsrc = (i == 0) ? 1 : 0;
        k_ln_part<XT><<<ROWS/4, 256, 0, stream>>>(src, dynsrc, flag,
                wb+OFF_N1W + i*CC, wb+OFF_N1B + i*CC, Hwin, shift);
        k_attn<XT><<<BB*NWIN, 512, 0, stream>>>(Hwin,
                wb+OFF_QKVW + (size_t)i*3*CC*CC, wb+OFF_QKVB + (size_t)i*3*CC,
                wb+OFF_RPB + (size_t)i*169*NHH,
                wb+OFF_PROJW + (size_t)i*CC*CC, wb+OFF_PROJB + i*CC,
                src, dynsrc, flag, X, i);
        k_mlp<XT><<<ROWS/64, 256, 0, stream>>>(X,
                wb+OFF_N2W + i*CC, wb+OFF_N2B + i*CC,
                wb+OFF_F1W + (size_t)i*4*CC*CC, wb+OFF_F1B + (size_t)i*4*CC,
                wb+OFF_F2W + (size_t)i*CC*4*CC, wb+OFF_F2B + i*CC);
    }
    k_out<XT><<<(int)(TOT/2048), 256, 0, stream>>>(X, out, flag);
}

extern "C" void kernel_launch(void* const* d_in, const int* in_sizes, int n_in,
                              void* d_out, int out_size, void* d_ws, size_t ws_size,
                              hipStream_t stream){
    char* p = (char*)d_ws;
    int*  flag = (int*)p;
    bf16* wb   = (bf16*)(p + 16);
    char* q    = p + 16 + (2u<<20);

    k_detect<<<1, 64, 0, stream>>>((const unsigned short*)d_in[1], flag);

    static const int widx[13] = {1,2,3,4,5,6,7,8,9,10,11,12,13};
    static const int woff[13] = {OFF_N1W,OFF_N1B,OFF_QKVW,OFF_QKVB,OFF_RPB,
                                 OFF_PROJW,OFF_PROJB,OFF_N2W,OFF_N2B,
                                 OFF_F1W,OFF_F1B,OFF_F2W,OFF_F2B};
    static const int wsz[13]  = {384,384,221184,1152,2028,73728,384,384,384,
                                 294912,1536,294912,384};
    for (int k = 0; k < 13; ++k)
        k_canon<<<(wsz[k]+255)/256, 256, 0, stream>>>(d_in[widx[k]], wb+woff[k],
                                                      wsz[k], flag);

    size_t needF32 = 16 + (2u<<20) + TOT*4 + TOT*2;
    if (ws_size >= needF32){
        float* X   = (float*)q;       q += TOT*4;
        bf16* Hwin = (bf16*)q;
        run_pipeline<float>(wb, d_in[0], flag, X, Hwin, d_out, stream);
    } else {
        bf16* X    = (bf16*)q;        q += TOT*2;
        bf16* Hwin = (bf16*)q;
        run_pipeline<bf16>(wb, d_in[0], flag, X, Hwin, d_out, stream);
    }
}